// Round 8
// baseline (242.823 us; speedup 1.0000x reference)
//
#include <hip/hip_runtime.h>
#include <hip/hip_bf16.h>
#include <math.h>

// Problem constants
constexpr int Bn     = 2;
constexpr int Lseq   = 1024;
constexpr int DM     = 512;    // d_model
constexpr int DI     = 1024;   // d_inner
constexpr int DS     = 64;     // d_state
constexpr int RNK    = 32;     // dt_rank
constexpr int NROWS  = Bn * Lseq;  // 2048
constexpr int XDBW   = RNK + 2 * DS; // 160
constexpr int CH     = 64;     // scan tile length
constexpr int NC     = Lseq / CH;  // 16 tiles
constexpr int DROWS  = 8;      // delta kernel rows per block

constexpr float LOG2E = 1.44269504088896340736f;

typedef __attribute__((ext_vector_type(4))) float floatx4;
typedef __attribute__((ext_vector_type(8))) short shortx8;

__device__ __forceinline__ float silu_f(float v) {
    return v / (1.f + __expf(-v));
}

__device__ __forceinline__ float rdl(float v, int l) {
    return __int_as_float(__builtin_amdgcn_readlane(__float_as_int(v), l));
}

__device__ __forceinline__ float bf2f(unsigned short u) {
    return __uint_as_float((unsigned)u << 16);
}

// exp2 that maps straight to v_exp_f32 (no hidden ×log2e mul)
__device__ __forceinline__ float exp2_fast(float x) {
#if __has_builtin(__builtin_amdgcn_exp2f)
    return __builtin_amdgcn_exp2f(x);
#else
    return exp2f(x);
#endif
}

// ---------------- Fused prep: LN (blocks 0..2047) + 3 weight transposes (2048..2479) ----
__global__ void prep_kernel(const float* __restrict__ x, const float* __restrict__ g,
                            const float* __restrict__ be,
                            const float* __restrict__ Wi, const float* __restrict__ Wo,
                            const float* __restrict__ Wx,
                            __hip_bfloat16* __restrict__ xn,
                            __hip_bfloat16* __restrict__ Ti, __hip_bfloat16* __restrict__ To,
                            __hip_bfloat16* __restrict__ Tx) {
    __shared__ float tile[64][65];
    __shared__ float red[8];
    int bid = blockIdx.x;
    int tid = threadIdx.x;
    if (bid < NROWS) {
        int row = bid;
        const float* xr = x + (size_t)row * DM;
        float v0 = xr[tid], v1 = xr[tid + 256];
        float s = v0 + v1, sq = v0 * v0 + v1 * v1;
        #pragma unroll
        for (int o = 1; o < 64; o <<= 1) {
            s  += __shfl_xor(s, o);
            sq += __shfl_xor(sq, o);
        }
        int w = tid >> 6;
        if ((tid & 63) == 0) { red[w] = s; red[4 + w] = sq; }
        __syncthreads();
        float ts = red[0] + red[1] + red[2] + red[3];
        float tq = red[4] + red[5] + red[6] + red[7];
        float mu  = ts * (1.f / DM);
        float var = tq * (1.f / DM) - mu * mu;
        float inv = rsqrtf(var + 1e-5f);
        __hip_bfloat16* o0 = xn + (size_t)row * DM;
        o0[tid]       = __float2bfloat16((v0 - mu) * inv * g[tid]       + be[tid]);
        o0[tid + 256] = __float2bfloat16((v1 - mu) * inv * g[tid + 256] + be[tid + 256]);
        return;
    }
    int b2 = bid - NROWS;
    const float* in; __hip_bfloat16* out; int R, Cc, bx, by;
    if (b2 < 256)      { in = Wi; out = Ti; R = DM; Cc = 2 * DI; bx = b2 & 31; by = b2 >> 5; }
    else if (b2 < 384) { int b3 = b2 - 256; in = Wo; out = To; R = DI; Cc = DM;   bx = b3 & 7; by = b3 >> 3; }
    else               { int b3 = b2 - 384; in = Wx; out = Tx; R = DI; Cc = XDBW; bx = b3 % 3; by = b3 / 3; }
    int r0 = by * 64, c0 = bx * 64;
    #pragma unroll
    for (int i = tid; i < 4096; i += 256) {
        int r = i >> 6, c = i & 63;
        tile[r][c] = (r0 + r < R && c0 + c < Cc) ? in[(size_t)(r0 + r) * Cc + c0 + c] : 0.f;
    }
    __syncthreads();
    #pragma unroll
    for (int i = tid; i < 4096; i += 256) {
        int c = i >> 6, r = i & 63;
        if (r0 + r < R && c0 + c < Cc)
            out[(size_t)(c0 + c) * R + r0 + r] = __float2bfloat16(tile[r][c]);
    }
}

// ---------------- in_proj GEMM 128x128 tile, 512 thr, BK=64 (2 stacked 32-K panels) -----
__global__ __launch_bounds__(512) void gemm_inproj(const __hip_bfloat16* __restrict__ A,
                                                   const __hip_bfloat16* __restrict__ Bt,
                                                   __hip_bfloat16* __restrict__ xh,
                                                   __hip_bfloat16* __restrict__ zh,
                                                   int M, int N, int K) {
    __shared__ __hip_bfloat16 As[128 * 64];
    __shared__ __hip_bfloat16 Bs[128 * 64];
    const int tid  = threadIdx.x;
    const int wave = tid >> 6, lane = tid & 63;
    const int m0 = blockIdx.y * 128, n0 = blockIdx.x * 128;
    const int wm = (wave >> 2) * 64, wn = (wave & 3) * 32;

    floatx4 acc[4][2] = {};

    const int arow16 = lane & 15;
    const int kgrp   = lane >> 4;

    for (int k0 = 0; k0 < K; k0 += 64) {
        #pragma unroll
        for (int p = 0; p < 2; ++p) {
            int j = tid + p * 512;            // 0..1023 chunk index
            int h = j >> 9, rs = j & 511;
            int row = rs >> 2, seg = rs & 3;
            const __hip_bfloat16* gA = A  + (size_t)(m0 + row) * K + k0 + h * 32 + seg * 8;
            const __hip_bfloat16* gB = Bt + (size_t)(n0 + row) * K + k0 + h * 32 + seg * 8;
            __hip_bfloat16* lA = As + (size_t)(wave * 64 + p * 512) * 8;
            __hip_bfloat16* lB = Bs + (size_t)(wave * 64 + p * 512) * 8;
            __builtin_amdgcn_global_load_lds(
                (const __attribute__((address_space(1))) void*)gA,
                (__attribute__((address_space(3))) void*)lA, 16, 0, 0);
            __builtin_amdgcn_global_load_lds(
                (const __attribute__((address_space(1))) void*)gB,
                (__attribute__((address_space(3))) void*)lB, 16, 0, 0);
        }
        __syncthreads();

        const shortx8* Asv = (const shortx8*)As;
        const shortx8* Bsv = (const shortx8*)Bs;
        #pragma unroll
        for (int h = 0; h < 2; ++h) {
            shortx8 a[4], b[2];
            #pragma unroll
            for (int i = 0; i < 4; ++i)
                a[i] = Asv[h * 512 + (wm + i * 16 + arow16) * 4 + kgrp];
            #pragma unroll
            for (int j = 0; j < 2; ++j)
                b[j] = Bsv[h * 512 + (wn + j * 16 + arow16) * 4 + kgrp];
            #pragma unroll
            for (int i = 0; i < 4; ++i)
                #pragma unroll
                for (int j = 0; j < 2; ++j)
                    acc[i][j] = __builtin_amdgcn_mfma_f32_16x16x32_bf16(a[i], b[j], acc[i][j], 0, 0, 0);
        }
        __syncthreads();
    }

    const int drow = (lane >> 4) * 4;
    const int dcol = lane & 15;
    const bool isz = (n0 >= DI);
    __hip_bfloat16* dst = isz ? zh : xh;
    const int coloff = isz ? DI : 0;
    #pragma unroll
    for (int i = 0; i < 4; ++i)
        #pragma unroll
        for (int j = 0; j < 2; ++j) {
            int rowb = m0 + wm + i * 16 + drow;
            int col  = n0 + wn + j * 16 + dcol - coloff;
            #pragma unroll
            for (int r = 0; r < 4; ++r)
                dst[(size_t)(rowb + r) * DI + col] = __float2bfloat16(acc[i][j][r]);
        }
}

// ---------------- bf16 MFMA GEMM 64x64 tile, 512 thr, split-K, BK=64 (2 panels) ---------
template<bool RES>
__global__ __launch_bounds__(512) void gemm64_sk(const __hip_bfloat16* __restrict__ A,
                                                 const __hip_bfloat16* __restrict__ Bt,
                                                 const float* __restrict__ Res,
                                                 float* __restrict__ C,
                                                 int M, int N, int K) {
    __shared__ __hip_bfloat16 As[2][64 * 64];
    __shared__ __hip_bfloat16 Bs[2][64 * 64];
    __shared__ float red[256 * 17];
    const int tid  = threadIdx.x;
    const int wave = tid >> 6, lane = tid & 63;
    const int g = wave >> 2, w2 = wave & 3;
    const int m0 = blockIdx.y * 64, n0 = blockIdx.x * 64;
    const int wm = (w2 >> 1) * 32, wn = (w2 & 1) * 32;

    floatx4 acc[2][2] = {};

    const int arow16 = lane & 15;
    const int kgrp   = lane >> 4;
    const int kbeg   = g * (K / 2);

    for (int kk = 0; kk < K / 2; kk += 64) {
        int k0 = kbeg + kk;
        #pragma unroll
        for (int p = 0; p < 2; ++p) {
            int j = (w2 * 64 + lane) + p * 256;   // 0..511 chunk index within group
            int h = j >> 8, rs = j & 255;
            int row = rs >> 2, seg = rs & 3;
            int brow = n0 + row; if (brow >= N) brow = N - 1;
            const __hip_bfloat16* gA = A  + (size_t)(m0 + row) * K + k0 + h * 32 + seg * 8;
            const __hip_bfloat16* gB = Bt + (size_t)brow * K + k0 + h * 32 + seg * 8;
            __hip_bfloat16* lA = As[g] + (size_t)(w2 * 64 + p * 256) * 8;
            __hip_bfloat16* lB = Bs[g] + (size_t)(w2 * 64 + p * 256) * 8;
            __builtin_amdgcn_global_load_lds(
                (const __attribute__((address_space(1))) void*)gA,
                (__attribute__((address_space(3))) void*)lA, 16, 0, 0);
            __builtin_amdgcn_global_load_lds(
                (const __attribute__((address_space(1))) void*)gB,
                (__attribute__((address_space(3))) void*)lB, 16, 0, 0);
        }
        __syncthreads();

        const shortx8* Asv = (const shortx8*)As[g];
        const shortx8* Bsv = (const shortx8*)Bs[g];
        #pragma unroll
        for (int h = 0; h < 2; ++h) {
            shortx8 a[2], b[2];
            #pragma unroll
            for (int i = 0; i < 2; ++i)
                a[i] = Asv[h * 256 + (wm + i * 16 + arow16) * 4 + kgrp];
            #pragma unroll
            for (int j = 0; j < 2; ++j)
                b[j] = Bsv[h * 256 + (wn + j * 16 + arow16) * 4 + kgrp];
            #pragma unroll
            for (int i = 0; i < 2; ++i)
                #pragma unroll
                for (int j = 0; j < 2; ++j)
                    acc[i][j] = __builtin_amdgcn_mfma_f32_16x16x32_bf16(a[i], b[j], acc[i][j], 0, 0, 0);
        }
        __syncthreads();
    }

    int rbase = (w2 * 64 + lane) * 17;
    if (g == 1) {
        #pragma unroll
        for (int i = 0; i < 2; ++i)
            #pragma unroll
            for (int j = 0; j < 2; ++j)
                *(float4*)&red[rbase + (i * 2 + j) * 4] =
                    make_float4(acc[i][j][0], acc[i][j][1], acc[i][j][2], acc[i][j][3]);
    }
    __syncthreads();
    if (g == 0) {
        const int drow = (lane >> 4) * 4;
        const int dcol = lane & 15;
        #pragma unroll
        for (int i = 0; i < 2; ++i)
            #pragma unroll
            for (int j = 0; j < 2; ++j) {
                float4 part = *(const float4*)&red[rbase + (i * 2 + j) * 4];
                int rowb = m0 + wm + i * 16 + drow;
                int col  = n0 + wn + j * 16 + dcol;
                if (col < N) {
                    #pragma unroll
                    for (int r = 0; r < 4; ++r) {
                        size_t idx = (size_t)(rowb + r) * N + col;
                        float v = acc[i][j][r] + (&part.x)[r];
                        if (RES) v += Res[idx];
                        C[idx] = v;
                    }
                }
            }
    }
}

// ---------------- Tiled conv + silu + transposes ----------------
__global__ __launch_bounds__(256) void conv_tile(const __hip_bfloat16* __restrict__ xh,
                                                 const __hip_bfloat16* __restrict__ zh,
                                                 const float* __restrict__ cw,
                                                 const float* __restrict__ cb,
                                                 __hip_bfloat16* __restrict__ xcv_bf,
                                                 __hip_bfloat16* __restrict__ xcvT,
                                                 __hip_bfloat16* __restrict__ zgT) {
    __shared__ float xt[67][68];
    __shared__ float tb[64][65];    // conv+silu result [t][d]
    __shared__ float tb2[64][65];   // silu(z) [t][d]
    int t0 = blockIdx.x * 64, d0 = blockIdx.y * 64, b = blockIdx.z;
    int tid = threadIdx.x;
    size_t rowbase = (size_t)b * Lseq;

    for (int i = tid; i < 67 * 16; i += 256) {
        int r = i >> 4, j = i & 15;
        int t = t0 - 3 + r;
        float4 v4 = make_float4(0.f, 0.f, 0.f, 0.f);
        if (t >= 0) {
            ushort4 u = *(const ushort4*)&xh[(rowbase + t) * DI + d0 + j * 4];
            v4 = make_float4(bf2f(u.x), bf2f(u.y), bf2f(u.z), bf2f(u.w));
        }
        *(float4*)&xt[r][j * 4] = v4;
    }
    for (int i = tid; i < 64 * 16; i += 256) {
        int r = i >> 4, j = i & 15;
        ushort4 u = *(const ushort4*)&zh[(rowbase + t0 + r) * DI + d0 + j * 4];
        tb2[r][j * 4 + 0] = silu_f(bf2f(u.x));
        tb2[r][j * 4 + 1] = silu_f(bf2f(u.y));
        tb2[r][j * 4 + 2] = silu_f(bf2f(u.z));
        tb2[r][j * 4 + 3] = silu_f(bf2f(u.w));
    }
    __syncthreads();

    {
        int d = tid & 63, tg = tid >> 6;
        float4 cwv = *(const float4*)&cw[(d0 + d) * 4];
        float cbv = cb[d0 + d];
        #pragma unroll
        for (int i = 0; i < 16; ++i) {
            int t = tg * 16 + i;
            float acc = cbv;
            #pragma unroll
            for (int k = 0; k < 4; ++k) acc += xt[t + k][d] * (&cwv.x)[k];
            float v = silu_f(acc);
            tb[t][d] = v;
            xcv_bf[(rowbase + t0 + t) * DI + d0 + d] = __float2bfloat16(v);
        }
    }
    __syncthreads();

    {
        int t2 = tid & 63, dg2 = tid >> 6;
        #pragma unroll
        for (int i = 0; i < 16; ++i) {
            int d = dg2 * 16 + i;
            size_t orow = ((size_t)(b * DI + d0 + d)) * Lseq + t0 + t2;
            xcvT[orow] = __float2bfloat16(tb[t2][d]);
            zgT[orow]  = __float2bfloat16(tb2[t2][d]);
        }
    }
}

// ---------------- delta = softplus(dt @ W_dt + b_dt), 8 rows per block ----------------
__global__ __launch_bounds__(256) void delta_kernel(const float* __restrict__ xdb,
                                                    const float* __restrict__ Wdt,
                                                    const float* __restrict__ bdt,
                                                    float* __restrict__ delta) {
    int r0 = blockIdx.y * DROWS;
    int d = blockIdx.x * 256 + threadIdx.x;
    __shared__ float dtv[RNK][DROWS];   // [r][k] -> wave-uniform b128 reads
    if (threadIdx.x < DROWS * RNK) {
        int k = threadIdx.x >> 5, r = threadIdx.x & 31;
        dtv[r][k] = xdb[(size_t)(r0 + k) * XDBW + r];
    }
    __syncthreads();
    float bb = bdt[d];
    float acc[DROWS];
    #pragma unroll
    for (int k = 0; k < DROWS; ++k) acc[k] = bb;
    #pragma unroll
    for (int r = 0; r < RNK; ++r) {
        float wv = Wdt[(size_t)r * DI + d];
        float4 lo = *(const float4*)&dtv[r][0];
        float4 hi = *(const float4*)&dtv[r][4];
        acc[0] += lo.x * wv; acc[1] += lo.y * wv;
        acc[2] += lo.z * wv; acc[3] += lo.w * wv;
        acc[4] += hi.x * wv; acc[5] += hi.y * wv;
        acc[6] += hi.z * wv; acc[7] += hi.w * wv;
    }
    #pragma unroll
    for (int k = 0; k < DROWS; ++k) {
        float a = acc[k];
        float sp = (a > 20.f) ? a : log1pf(__expf(a));
        delta[(size_t)(r0 + k) * DI + d] = sp;
    }
}

// ============ Single-pass serial scan, LDS-pipe-optimized ============
// 1 channel/wave, h carried across all 16 tiles. B/C stored TRANSPOSED in LDS
// (BT[s][t], stride 68 -> 16B-aligned rows, even bank spread) so the compute
// loop reads them as ds_read_b128 (4 t per instr, 85 B/cyc vs b32's 44).
// P reduce reads widened to 2x b128 (stride 68, start banks 4tr+8q spread even).
// All delta staged upfront (dall). Same 2-barrier/tile dbuf discipline as v7.
__global__ __launch_bounds__(512) void scan_full(
        const float* __restrict__ delta, const __hip_bfloat16* __restrict__ xcvT,
        const float* __restrict__ xdb, const __hip_bfloat16* __restrict__ zgT,
        const float* __restrict__ A_log, const float* __restrict__ Dp,
        __hip_bfloat16* __restrict__ y_row) {
    __shared__ float BT[2][64][68];   // [buf][s][t] transposed B
    __shared__ float CT[2][64][68];   // [buf][s][t] transposed C
    __shared__ float dall[Lseq][9];   // [t][ch] all delta upfront
    __shared__ float P[8][8 * 68];    // per-wave reduce scratch, 16B-aligned rows
    __shared__ float T[64 * 9];       // y transpose staging [t][ch]

    int blk = blockIdx.x;              // Bn * DI/8 = 256
    int dg  = blk & 127;               // DI/8 = 128
    int b   = blk >> 7;
    int tid = threadIdx.x, w = tid >> 6, lane = tid & 63;
    int d = dg * 8 + w;

    float a2 = -__expf(A_log[d * DS + lane]) * LOG2E;  // exp(x) == exp2(x*log2e)
    float Dv = Dp[d];

    const int st_t = tid >> 3, st_d = tid & 7;

    // stage ALL delta for this block's 8 channels (1024 t x 8 ch)
    #pragma unroll
    for (int k = 0; k < 16; ++k) {
        int i = tid + k * 512;
        int t = i >> 3, ch = i & 7;
        dall[t][ch] = delta[(size_t)(b * Lseq + t) * DI + dg * 8 + ch];
    }
    // stage tile 0 B/C (transposed write)
    #pragma unroll
    for (int k = 0; k < 2; ++k) {
        int i = tid + k * 512;
        int t = i >> 4, sg = i & 15;
        const float* rowp = &xdb[(size_t)(b * Lseq + t) * XDBW + RNK];
        float4 bv = *(const float4*)&rowp[sg * 4];
        float4 cv = *(const float4*)&rowp[DS + sg * 4];
        #pragma unroll
        for (int j = 0; j < 4; ++j) {
            BT[0][4 * sg + j][t] = (&bv.x)[j];
            CT[0][4 * sg + j][t] = (&cv.x)[j];
        }
    }
    __syncthreads();

    const unsigned short* xT = (const unsigned short*)xcvT;
    const unsigned short* zT = (const unsigned short*)zgT;
    const size_t chbase = (size_t)(b * DI + d) * Lseq;

    float xv = bf2f(xT[chbase + lane]);   // tile 0 x/z prefetched
    float zv = bf2f(zT[chbase + lane]);

    float h = 0.f;
    float* Pw = (float*)P[w];
    const int tr = lane & 7, q = lane >> 3;
    const int rdbase = tr * 68 + q * 8;

    for (int c = 0; c < NC; ++c) {
        int cur = c & 1;

        // ---- issue register prefetch for tile c+1 (completes under the compute) ----
        float4 pb0, pc0, pb1, pc1;
        float nxv = 0.f, nzv = 0.f;
        if (c + 1 < NC) {
            int r1 = b * Lseq + (c + 1) * CH;
            {
                int t = tid >> 4, sg = tid & 15;
                const float* rowp = &xdb[(size_t)(r1 + t) * XDBW + RNK];
                pb0 = *(const float4*)&rowp[sg * 4];
                pc0 = *(const float4*)&rowp[DS + sg * 4];
            }
            {
                int i = tid + 512;
                int t = i >> 4, sg = i & 15;
                const float* rowp = &xdb[(size_t)(r1 + t) * XDBW + RNK];
                pb1 = *(const float4*)&rowp[sg * 4];
                pc1 = *(const float4*)&rowp[DS + sg * 4];
            }
            nxv = bf2f(xT[chbase + (c + 1) * CH + lane]);
            nzv = bf2f(zT[chbase + (c + 1) * CH + lane]);
        }

        // ---- compute tile c ----
        float vd  = dall[(c << 6) + lane][w];   // delta_t for t = lane
        float vpx = vd * xv;                    // delta_t * x_t
        float y = 0.f;
        const float* Bt = &BT[cur][lane][0];    // lane = state s
        const float* Ct = &CT[cur][lane][0];

        #pragma unroll
        for (int t8 = 0; t8 < 8; ++t8) {
            float4 b0 = *(const float4*)&Bt[t8 * 8];
            float4 b1 = *(const float4*)&Bt[t8 * 8 + 4];
            float4 c0 = *(const float4*)&Ct[t8 * 8];
            float4 c1 = *(const float4*)&Ct[t8 * 8 + 4];
            #pragma unroll
            for (int tt = 0; tt < 8; ++tt) {
                int t = t8 * 8 + tt;
                float Bv = (tt < 4) ? (&b0.x)[tt] : (&b1.x)[tt - 4];
                float Cv = (tt < 4) ? (&c0.x)[tt] : (&c1.x)[tt - 4];
                h = h * exp2_fast(rdl(vd, t) * a2) + rdl(vpx, t) * Bv;
                Pw[tt * 68 + lane] = h * Cv;
            }
            // reduce: 2x b128 + sequential adds (same order as prior scalar loop)
            float4 ra = *(const float4*)&Pw[rdbase];
            float4 rb = *(const float4*)&Pw[rdbase + 4];
            float sacc = ra.x + ra.y + ra.z + ra.w + rb.x + rb.y + rb.z + rb.w;
            sacc += __shfl_xor(sacc, 8);
            sacc += __shfl_xor(sacc, 16);
            sacc += __shfl_xor(sacc, 32);
            if (q == t8) y = sacc;       // lane l ends with y for t = l
        }

        float yv = (y + xv * Dv) * zv;

        __syncthreads();   // all waves done reading BT/CT[cur] + prior tile's T reads
        T[lane * 9 + w] = yv;
        if (c + 1 < NC) {
            int nxt = cur ^ 1;
            {
                int t = tid >> 4, sg = tid & 15;
                #pragma unroll
                for (int j = 0; j < 4; ++j) {
                    BT[nxt][4 * sg + j][t] = (&pb0.x)[j];
                    CT[nxt][4 * sg + j][t] = (&pc0.x)[j];
                }
            }
            {
                int i = tid + 512;
                int t = i >> 4, sg = i & 15;
                #pragma unroll
                for (int j = 0; j < 4; ++j) {
                    BT[nxt][4 * sg + j][t] = (&pb1.x)[j];
                    CT[nxt][4 * sg + j][t] = (&pc1.x)[j];
                }
            }
        }
        __syncthreads();   // T + next buf visible to all

        // coalesced y_row write from T
        {
            float v = T[st_t * 9 + st_d];
            y_row[(size_t)(b * Lseq + c * CH + st_t) * DI + dg * 8 + st_d] = __float2bfloat16(v);
        }

        xv = nxv; zv = nzv;
    }
}

extern "C" void kernel_launch(void* const* d_in, const int* in_sizes, int n_in,
                              void* d_out, int out_size, void* d_ws, size_t ws_size,
                              hipStream_t stream) {
    const float* frames = (const float*)d_in[0];
    const float* gamma  = (const float*)d_in[1];
    const float* beta   = (const float*)d_in[2];
    const float* W_in   = (const float*)d_in[3];
    const float* conv_w = (const float*)d_in[4];
    const float* conv_b = (const float*)d_in[5];
    const float* W_x    = (const float*)d_in[6];
    const float* W_dt   = (const float*)d_in[7];
    const float* b_dt   = (const float*)d_in[8];
    const float* A_log  = (const float*)d_in[9];
    const float* Dp     = (const float*)d_in[10];
    const float* W_out  = (const float*)d_in[11];
    float* out = (float*)d_out;

    // workspace carve-up (bytes)
    char* ws = (char*)d_ws;
    __hip_bfloat16* xn_bf  = (__hip_bfloat16*)ws; ws += (size_t)NROWS * DM * 2;
    __hip_bfloat16* Wt_in  = (__hip_bfloat16*)ws; ws += (size_t)(2 * DI) * DM * 2;
    __hip_bfloat16* Wt_out = (__hip_bfloat16*)ws; ws += (size_t)DM * DI * 2;
    __hip_bfloat16* Wt_x   = (__hip_bfloat16*)ws; ws += (size_t)XDBW * DI * 2;
    __hip_bfloat16* y_row  = (__hip_bfloat16*)ws; ws += (size_t)NROWS * DI * 2;
    __hip_bfloat16* xcv_bf = (__hip_bfloat16*)ws; ws += (size_t)NROWS * DI * 2;
    __hip_bfloat16* xh     = (__hip_bfloat16*)ws; ws += (size_t)NROWS * DI * 2;
    __hip_bfloat16* zh     = (__hip_bfloat16*)ws; ws += (size_t)NROWS * DI * 2;
    __hip_bfloat16* xcvT   = (__hip_bfloat16*)ws; ws += (size_t)NROWS * DI * 2;
    __hip_bfloat16* zgT    = (__hip_bfloat16*)ws; ws += (size_t)NROWS * DI * 2;
    float* xdb    = (float*)ws;  ws += (size_t)NROWS * XDBW * 4;
    float* delta  = (float*)ws;  ws += (size_t)NROWS * DI * 4;

    // fused LN + weight transposes
    prep_kernel<<<NROWS + 432, 256, 0, stream>>>(frames, gamma, beta, W_in, W_out, W_x,
                                                 xn_bf, Wt_in, Wt_out, Wt_x);

    // in_proj -> bf16 x-half / z-half (BK=64)
    gemm_inproj<<<dim3(2 * DI / 128, NROWS / 128), 512, 0, stream>>>(
        xn_bf, Wt_in, xh, zh, NROWS, 2 * DI, DM);

    // conv + silu + transposes
    conv_tile<<<dim3(Lseq / 64, DI / 64, Bn), 256, 0, stream>>>(
        xh, zh, conv_w, conv_b, xcv_bf, xcvT, zgT);

    // xdb = xcv @ W_x  (M=2048, N=160, K=1024, BK=64 split-K)
    gemm64_sk<false><<<dim3((XDBW + 63) / 64, NROWS / 64), 512, 0, stream>>>(
        xcv_bf, Wt_x, nullptr, xdb, NROWS, XDBW, DI);

    delta_kernel<<<dim3(DI / 256, NROWS / DROWS), 256, 0, stream>>>(xdb, W_dt, b_dt, delta);

    // single-pass serial selective scan
    scan_full<<<Bn * (DI / 8), 512, 0, stream>>>(delta, xcvT, xdb, zgT, A_log, Dp, y_row);

    // out_proj: out = y_row @ W_out + frames (BK=64 split-K)
    gemm64_sk<true><<<dim3(DM / 64, NROWS / 64), 512, 0, stream>>>(
        y_row, Wt_out, frames, out, NROWS, DM, DI);
}

// Round 9
// 223.280 us; speedup vs baseline: 1.0875x; 1.0875x over previous
//
#include <hip/hip_runtime.h>
#include <hip/hip_bf16.h>
#include <math.h>

// Problem constants
constexpr int Bn     = 2;
constexpr int Lseq   = 1024;
constexpr int DM     = 512;    // d_model
constexpr int DI     = 1024;   // d_inner
constexpr int DS     = 64;     // d_state
constexpr int RNK    = 32;     // dt_rank
constexpr int NROWS  = Bn * Lseq;  // 2048
constexpr int XDBW   = RNK + 2 * DS; // 160
constexpr int CH     = 64;     // scan tile length
constexpr int NC     = Lseq / CH;  // 16 tiles
constexpr int DROWS  = 8;      // delta kernel rows per block

constexpr float LOG2E = 1.44269504088896340736f;

typedef __attribute__((ext_vector_type(4))) float floatx4;
typedef __attribute__((ext_vector_type(8))) short shortx8;

__device__ __forceinline__ float silu_f(float v) {
    return v / (1.f + __expf(-v));
}

__device__ __forceinline__ float rdl(float v, int l) {
    return __int_as_float(__builtin_amdgcn_readlane(__float_as_int(v), l));
}

__device__ __forceinline__ float bf2f(unsigned short u) {
    return __uint_as_float((unsigned)u << 16);
}

// exp2 that maps straight to v_exp_f32 (no hidden ×log2e mul)
__device__ __forceinline__ float exp2_fast(float x) {
#if __has_builtin(__builtin_amdgcn_exp2f)
    return __builtin_amdgcn_exp2f(x);
#else
    return exp2f(x);
#endif
}

// ---------------- Fused prep: LN (blocks 0..2047) + 3 weight transposes (2048..2479) ----
__global__ void prep_kernel(const float* __restrict__ x, const float* __restrict__ g,
                            const float* __restrict__ be,
                            const float* __restrict__ Wi, const float* __restrict__ Wo,
                            const float* __restrict__ Wx,
                            __hip_bfloat16* __restrict__ xn,
                            __hip_bfloat16* __restrict__ Ti, __hip_bfloat16* __restrict__ To,
                            __hip_bfloat16* __restrict__ Tx) {
    __shared__ float tile[64][65];
    __shared__ float red[8];
    int bid = blockIdx.x;
    int tid = threadIdx.x;
    if (bid < NROWS) {
        int row = bid;
        const float* xr = x + (size_t)row * DM;
        float v0 = xr[tid], v1 = xr[tid + 256];
        float s = v0 + v1, sq = v0 * v0 + v1 * v1;
        #pragma unroll
        for (int o = 1; o < 64; o <<= 1) {
            s  += __shfl_xor(s, o);
            sq += __shfl_xor(sq, o);
        }
        int w = tid >> 6;
        if ((tid & 63) == 0) { red[w] = s; red[4 + w] = sq; }
        __syncthreads();
        float ts = red[0] + red[1] + red[2] + red[3];
        float tq = red[4] + red[5] + red[6] + red[7];
        float mu  = ts * (1.f / DM);
        float var = tq * (1.f / DM) - mu * mu;
        float inv = rsqrtf(var + 1e-5f);
        __hip_bfloat16* o0 = xn + (size_t)row * DM;
        o0[tid]       = __float2bfloat16((v0 - mu) * inv * g[tid]       + be[tid]);
        o0[tid + 256] = __float2bfloat16((v1 - mu) * inv * g[tid + 256] + be[tid + 256]);
        return;
    }
    int b2 = bid - NROWS;
    const float* in; __hip_bfloat16* out; int R, Cc, bx, by;
    if (b2 < 256)      { in = Wi; out = Ti; R = DM; Cc = 2 * DI; bx = b2 & 31; by = b2 >> 5; }
    else if (b2 < 384) { int b3 = b2 - 256; in = Wo; out = To; R = DI; Cc = DM;   bx = b3 & 7; by = b3 >> 3; }
    else               { int b3 = b2 - 384; in = Wx; out = Tx; R = DI; Cc = XDBW; bx = b3 % 3; by = b3 / 3; }
    int r0 = by * 64, c0 = bx * 64;
    #pragma unroll
    for (int i = tid; i < 4096; i += 256) {
        int r = i >> 6, c = i & 63;
        tile[r][c] = (r0 + r < R && c0 + c < Cc) ? in[(size_t)(r0 + r) * Cc + c0 + c] : 0.f;
    }
    __syncthreads();
    #pragma unroll
    for (int i = tid; i < 4096; i += 256) {
        int c = i >> 6, r = i & 63;
        if (r0 + r < R && c0 + c < Cc)
            out[(size_t)(c0 + c) * R + r0 + r] = __float2bfloat16(tile[r][c]);
    }
}

// ---------------- in_proj GEMM 128x128 tile, 512 thr, BK=64 (2 stacked 32-K panels) -----
__global__ __launch_bounds__(512) void gemm_inproj(const __hip_bfloat16* __restrict__ A,
                                                   const __hip_bfloat16* __restrict__ Bt,
                                                   __hip_bfloat16* __restrict__ xh,
                                                   __hip_bfloat16* __restrict__ zh,
                                                   int M, int N, int K) {
    __shared__ __hip_bfloat16 As[128 * 64];
    __shared__ __hip_bfloat16 Bs[128 * 64];
    const int tid  = threadIdx.x;
    const int wave = tid >> 6, lane = tid & 63;
    const int m0 = blockIdx.y * 128, n0 = blockIdx.x * 128;
    const int wm = (wave >> 2) * 64, wn = (wave & 3) * 32;

    floatx4 acc[4][2] = {};

    const int arow16 = lane & 15;
    const int kgrp   = lane >> 4;

    for (int k0 = 0; k0 < K; k0 += 64) {
        #pragma unroll
        for (int p = 0; p < 2; ++p) {
            int j = tid + p * 512;            // 0..1023 chunk index
            int h = j >> 9, rs = j & 511;
            int row = rs >> 2, seg = rs & 3;
            const __hip_bfloat16* gA = A  + (size_t)(m0 + row) * K + k0 + h * 32 + seg * 8;
            const __hip_bfloat16* gB = Bt + (size_t)(n0 + row) * K + k0 + h * 32 + seg * 8;
            __hip_bfloat16* lA = As + (size_t)(wave * 64 + p * 512) * 8;
            __hip_bfloat16* lB = Bs + (size_t)(wave * 64 + p * 512) * 8;
            __builtin_amdgcn_global_load_lds(
                (const __attribute__((address_space(1))) void*)gA,
                (__attribute__((address_space(3))) void*)lA, 16, 0, 0);
            __builtin_amdgcn_global_load_lds(
                (const __attribute__((address_space(1))) void*)gB,
                (__attribute__((address_space(3))) void*)lB, 16, 0, 0);
        }
        __syncthreads();

        const shortx8* Asv = (const shortx8*)As;
        const shortx8* Bsv = (const shortx8*)Bs;
        #pragma unroll
        for (int h = 0; h < 2; ++h) {
            shortx8 a[4], b[2];
            #pragma unroll
            for (int i = 0; i < 4; ++i)
                a[i] = Asv[h * 512 + (wm + i * 16 + arow16) * 4 + kgrp];
            #pragma unroll
            for (int j = 0; j < 2; ++j)
                b[j] = Bsv[h * 512 + (wn + j * 16 + arow16) * 4 + kgrp];
            #pragma unroll
            for (int i = 0; i < 4; ++i)
                #pragma unroll
                for (int j = 0; j < 2; ++j)
                    acc[i][j] = __builtin_amdgcn_mfma_f32_16x16x32_bf16(a[i], b[j], acc[i][j], 0, 0, 0);
        }
        __syncthreads();
    }

    const int drow = (lane >> 4) * 4;
    const int dcol = lane & 15;
    const bool isz = (n0 >= DI);
    __hip_bfloat16* dst = isz ? zh : xh;
    const int coloff = isz ? DI : 0;
    #pragma unroll
    for (int i = 0; i < 4; ++i)
        #pragma unroll
        for (int j = 0; j < 2; ++j) {
            int rowb = m0 + wm + i * 16 + drow;
            int col  = n0 + wn + j * 16 + dcol - coloff;
            #pragma unroll
            for (int r = 0; r < 4; ++r)
                dst[(size_t)(rowb + r) * DI + col] = __float2bfloat16(acc[i][j][r]);
        }
}

// ---------------- bf16 MFMA GEMM 64x64 tile, 512 thr, split-K, BK=64 (2 panels) ---------
template<bool RES>
__global__ __launch_bounds__(512) void gemm64_sk(const __hip_bfloat16* __restrict__ A,
                                                 const __hip_bfloat16* __restrict__ Bt,
                                                 const float* __restrict__ Res,
                                                 float* __restrict__ C,
                                                 int M, int N, int K) {
    __shared__ __hip_bfloat16 As[2][64 * 64];
    __shared__ __hip_bfloat16 Bs[2][64 * 64];
    __shared__ float red[256 * 17];
    const int tid  = threadIdx.x;
    const int wave = tid >> 6, lane = tid & 63;
    const int g = wave >> 2, w2 = wave & 3;
    const int m0 = blockIdx.y * 64, n0 = blockIdx.x * 64;
    const int wm = (w2 >> 1) * 32, wn = (w2 & 1) * 32;

    floatx4 acc[2][2] = {};

    const int arow16 = lane & 15;
    const int kgrp   = lane >> 4;
    const int kbeg   = g * (K / 2);

    for (int kk = 0; kk < K / 2; kk += 64) {
        int k0 = kbeg + kk;
        #pragma unroll
        for (int p = 0; p < 2; ++p) {
            int j = (w2 * 64 + lane) + p * 256;   // 0..511 chunk index within group
            int h = j >> 8, rs = j & 255;
            int row = rs >> 2, seg = rs & 3;
            int brow = n0 + row; if (brow >= N) brow = N - 1;
            const __hip_bfloat16* gA = A  + (size_t)(m0 + row) * K + k0 + h * 32 + seg * 8;
            const __hip_bfloat16* gB = Bt + (size_t)brow * K + k0 + h * 32 + seg * 8;
            __hip_bfloat16* lA = As[g] + (size_t)(w2 * 64 + p * 256) * 8;
            __hip_bfloat16* lB = Bs[g] + (size_t)(w2 * 64 + p * 256) * 8;
            __builtin_amdgcn_global_load_lds(
                (const __attribute__((address_space(1))) void*)gA,
                (__attribute__((address_space(3))) void*)lA, 16, 0, 0);
            __builtin_amdgcn_global_load_lds(
                (const __attribute__((address_space(1))) void*)gB,
                (__attribute__((address_space(3))) void*)lB, 16, 0, 0);
        }
        __syncthreads();

        const shortx8* Asv = (const shortx8*)As[g];
        const shortx8* Bsv = (const shortx8*)Bs[g];
        #pragma unroll
        for (int h = 0; h < 2; ++h) {
            shortx8 a[2], b[2];
            #pragma unroll
            for (int i = 0; i < 2; ++i)
                a[i] = Asv[h * 256 + (wm + i * 16 + arow16) * 4 + kgrp];
            #pragma unroll
            for (int j = 0; j < 2; ++j)
                b[j] = Bsv[h * 256 + (wn + j * 16 + arow16) * 4 + kgrp];
            #pragma unroll
            for (int i = 0; i < 2; ++i)
                #pragma unroll
                for (int j = 0; j < 2; ++j)
                    acc[i][j] = __builtin_amdgcn_mfma_f32_16x16x32_bf16(a[i], b[j], acc[i][j], 0, 0, 0);
        }
        __syncthreads();
    }

    int rbase = (w2 * 64 + lane) * 17;
    if (g == 1) {
        #pragma unroll
        for (int i = 0; i < 2; ++i)
            #pragma unroll
            for (int j = 0; j < 2; ++j)
                *(float4*)&red[rbase + (i * 2 + j) * 4] =
                    make_float4(acc[i][j][0], acc[i][j][1], acc[i][j][2], acc[i][j][3]);
    }
    __syncthreads();
    if (g == 0) {
        const int drow = (lane >> 4) * 4;
        const int dcol = lane & 15;
        #pragma unroll
        for (int i = 0; i < 2; ++i)
            #pragma unroll
            for (int j = 0; j < 2; ++j) {
                float4 part = *(const float4*)&red[rbase + (i * 2 + j) * 4];
                int rowb = m0 + wm + i * 16 + drow;
                int col  = n0 + wn + j * 16 + dcol;
                if (col < N) {
                    #pragma unroll
                    for (int r = 0; r < 4; ++r) {
                        size_t idx = (size_t)(rowb + r) * N + col;
                        float v = acc[i][j][r] + (&part.x)[r];
                        if (RES) v += Res[idx];
                        C[idx] = v;
                    }
                }
            }
    }
}

// ---------------- Tiled conv + silu + transposes ----------------
__global__ __launch_bounds__(256) void conv_tile(const __hip_bfloat16* __restrict__ xh,
                                                 const __hip_bfloat16* __restrict__ zh,
                                                 const float* __restrict__ cw,
                                                 const float* __restrict__ cb,
                                                 __hip_bfloat16* __restrict__ xcv_bf,
                                                 __hip_bfloat16* __restrict__ xcvT,
                                                 __hip_bfloat16* __restrict__ zgT) {
    __shared__ float xt[67][68];
    __shared__ float tb[64][65];    // conv+silu result [t][d]
    __shared__ float tb2[64][65];   // silu(z) [t][d]
    int t0 = blockIdx.x * 64, d0 = blockIdx.y * 64, b = blockIdx.z;
    int tid = threadIdx.x;
    size_t rowbase = (size_t)b * Lseq;

    for (int i = tid; i < 67 * 16; i += 256) {
        int r = i >> 4, j = i & 15;
        int t = t0 - 3 + r;
        float4 v4 = make_float4(0.f, 0.f, 0.f, 0.f);
        if (t >= 0) {
            ushort4 u = *(const ushort4*)&xh[(rowbase + t) * DI + d0 + j * 4];
            v4 = make_float4(bf2f(u.x), bf2f(u.y), bf2f(u.z), bf2f(u.w));
        }
        *(float4*)&xt[r][j * 4] = v4;
    }
    for (int i = tid; i < 64 * 16; i += 256) {
        int r = i >> 4, j = i & 15;
        ushort4 u = *(const ushort4*)&zh[(rowbase + t0 + r) * DI + d0 + j * 4];
        tb2[r][j * 4 + 0] = silu_f(bf2f(u.x));
        tb2[r][j * 4 + 1] = silu_f(bf2f(u.y));
        tb2[r][j * 4 + 2] = silu_f(bf2f(u.z));
        tb2[r][j * 4 + 3] = silu_f(bf2f(u.w));
    }
    __syncthreads();

    {
        int d = tid & 63, tg = tid >> 6;
        float4 cwv = *(const float4*)&cw[(d0 + d) * 4];
        float cbv = cb[d0 + d];
        #pragma unroll
        for (int i = 0; i < 16; ++i) {
            int t = tg * 16 + i;
            float acc = cbv;
            #pragma unroll
            for (int k = 0; k < 4; ++k) acc += xt[t + k][d] * (&cwv.x)[k];
            float v = silu_f(acc);
            tb[t][d] = v;
            xcv_bf[(rowbase + t0 + t) * DI + d0 + d] = __float2bfloat16(v);
        }
    }
    __syncthreads();

    {
        int t2 = tid & 63, dg2 = tid >> 6;
        #pragma unroll
        for (int i = 0; i < 16; ++i) {
            int d = dg2 * 16 + i;
            size_t orow = ((size_t)(b * DI + d0 + d)) * Lseq + t0 + t2;
            xcvT[orow] = __float2bfloat16(tb[t2][d]);
            zgT[orow]  = __float2bfloat16(tb2[t2][d]);
        }
    }
}

// ---------------- delta = softplus(dt @ W_dt + b_dt), 8 rows per block ----------------
__global__ __launch_bounds__(256) void delta_kernel(const float* __restrict__ xdb,
                                                    const float* __restrict__ Wdt,
                                                    const float* __restrict__ bdt,
                                                    float* __restrict__ delta) {
    int r0 = blockIdx.y * DROWS;
    int d = blockIdx.x * 256 + threadIdx.x;
    __shared__ float dtv[RNK][DROWS];   // [r][k] -> wave-uniform b128 reads
    if (threadIdx.x < DROWS * RNK) {
        int k = threadIdx.x >> 5, r = threadIdx.x & 31;
        dtv[r][k] = xdb[(size_t)(r0 + k) * XDBW + r];
    }
    __syncthreads();
    float bb = bdt[d];
    float acc[DROWS];
    #pragma unroll
    for (int k = 0; k < DROWS; ++k) acc[k] = bb;
    #pragma unroll
    for (int r = 0; r < RNK; ++r) {
        float wv = Wdt[(size_t)r * DI + d];
        float4 lo = *(const float4*)&dtv[r][0];
        float4 hi = *(const float4*)&dtv[r][4];
        acc[0] += lo.x * wv; acc[1] += lo.y * wv;
        acc[2] += lo.z * wv; acc[3] += lo.w * wv;
        acc[4] += hi.x * wv; acc[5] += hi.y * wv;
        acc[6] += hi.z * wv; acc[7] += hi.w * wv;
    }
    #pragma unroll
    for (int k = 0; k < DROWS; ++k) {
        float a = acc[k];
        float sp = (a > 20.f) ? a : log1pf(__expf(a));
        delta[(size_t)(r0 + k) * DI + d] = sp;
    }
}

// ============ Single-pass serial scan: 1 channel per wave, h carried across all 16 tiles
// v7 structure (proven 77.8 us) with ONE change: B and C paired as float2 in LDS
// -> the per-t compute does 1 ds_read_b64 (b64 floor: each bank touched exactly 4x,
// conflict-free) instead of 2 ds_read_b32. ~23% of the LDS-pipe budget removed.
// All other geometry (linear staging writes, stride-65 scalar P reduce, dsh, barriers)
// byte-identical to v7. Arithmetic order unchanged -> bit-exact vs v7.
__global__ __launch_bounds__(512) void scan_full(
        const float* __restrict__ delta, const __hip_bfloat16* __restrict__ xcvT,
        const float* __restrict__ xdb, const __hip_bfloat16* __restrict__ zgT,
        const float* __restrict__ A_log, const float* __restrict__ Dp,
        __hip_bfloat16* __restrict__ y_row) {
    __shared__ float2 BC[2][64][65];   // [buf][t][s] = {B, C}; row = 65 float2 (520 B)
    __shared__ float dsh[2][64][9];    // [buf][t][ch] (stride 9: 2-way max on r/w)
    __shared__ float P[8][8 * 65];     // per-wave reduce scratch, odd stride 65
    __shared__ float T[64 * 9];        // y transpose staging [t][ch]

    int blk = blockIdx.x;              // Bn * DI/8 = 256
    int dg  = blk & 127;               // DI/8 = 128
    int b   = blk >> 7;
    int tid = threadIdx.x, w = tid >> 6, lane = tid & 63;
    int d = dg * 8 + w;

    float a2 = -__expf(A_log[d * DS + lane]) * LOG2E;  // exp(x) == exp2(x*log2e)
    float Dv = Dp[d];

    const int st_t = tid >> 3, st_d = tid & 7;

    // stage tile 0 directly (interleaved {B,C} pairs)
    {
        int r0 = b * Lseq;
        #pragma unroll
        for (int k = 0; k < 2; ++k) {
            int i = tid + k * 512;
            int t = i >> 4, sg = i & 15;
            const float* rowp = &xdb[(size_t)(r0 + t) * XDBW + RNK];
            float4 bv = *(const float4*)&rowp[sg * 4];
            float4 cv = *(const float4*)&rowp[DS + sg * 4];
            #pragma unroll
            for (int j = 0; j < 4; ++j)
                BC[0][t][sg * 4 + j] = make_float2((&bv.x)[j], (&cv.x)[j]);
        }
        dsh[0][st_t][st_d] = delta[(size_t)(r0 + st_t) * DI + dg * 8 + st_d];
    }
    __syncthreads();

    const unsigned short* xT = (const unsigned short*)xcvT;
    const unsigned short* zT = (const unsigned short*)zgT;
    const size_t chbase = (size_t)(b * DI + d) * Lseq;

    float xv = bf2f(xT[chbase + lane]);   // tile 0 x/z prefetched
    float zv = bf2f(zT[chbase + lane]);

    float h = 0.f;
    float* Pw = P[w];
    const int tr = lane & 7, q = lane >> 3;
    const int rdbase = tr * 65 + q * 8;

    for (int c = 0; c < NC; ++c) {
        int cur = c & 1;

        // ---- issue register prefetch for tile c+1 (completes under the compute) ----
        float4 pb0, pc0, pb1, pc1;
        float pd = 0.f, nxv = 0.f, nzv = 0.f;
        if (c + 1 < NC) {
            int r1 = b * Lseq + (c + 1) * CH;
            {
                int t = tid >> 4, sg = tid & 15;
                const float* rowp = &xdb[(size_t)(r1 + t) * XDBW + RNK];
                pb0 = *(const float4*)&rowp[sg * 4];
                pc0 = *(const float4*)&rowp[DS + sg * 4];
            }
            {
                int i = tid + 512;
                int t = i >> 4, sg = i & 15;
                const float* rowp = &xdb[(size_t)(r1 + t) * XDBW + RNK];
                pb1 = *(const float4*)&rowp[sg * 4];
                pc1 = *(const float4*)&rowp[DS + sg * 4];
            }
            pd  = delta[(size_t)(r1 + st_t) * DI + dg * 8 + st_d];
            nxv = bf2f(xT[chbase + (c + 1) * CH + lane]);
            nzv = bf2f(zT[chbase + (c + 1) * CH + lane]);
        }

        // ---- compute tile c ----
        int r0 = b * Lseq + c * CH;
        float vd  = dsh[cur][lane][w];   // delta_t for t = lane
        float vpx = vd * xv;             // delta_t * x_t
        float y = 0.f;

        #pragma unroll
        for (int t8 = 0; t8 < 8; ++t8) {
            #pragma unroll
            for (int tt = 0; tt < 8; ++tt) {
                int t = t8 * 8 + tt;
                float2 bc = BC[cur][t][lane];    // one ds_read_b64: {B_t[s], C_t[s]}
                h = h * exp2_fast(rdl(vd, t) * a2) + rdl(vpx, t) * bc.x;
                Pw[tt * 65 + lane] = h * bc.y;
            }
            float sacc = 0.f;
            #pragma unroll
            for (int j = 0; j < 8; ++j) sacc += Pw[rdbase + j];
            sacc += __shfl_xor(sacc, 8);
            sacc += __shfl_xor(sacc, 16);
            sacc += __shfl_xor(sacc, 32);
            if (q == t8) y = sacc;       // lane l ends with y for t = l
        }

        float yv = (y + xv * Dv) * zv;

        __syncthreads();   // all waves done reading buf[cur] + prior tile's T reads
        T[lane * 9 + w] = yv;
        if (c + 1 < NC) {
            int nxt = cur ^ 1;
            {
                int t = tid >> 4, sg = tid & 15;
                #pragma unroll
                for (int j = 0; j < 4; ++j)
                    BC[nxt][t][sg * 4 + j] = make_float2((&pb0.x)[j], (&pc0.x)[j]);
            }
            {
                int i = tid + 512;
                int t = i >> 4, sg = i & 15;
                #pragma unroll
                for (int j = 0; j < 4; ++j)
                    BC[nxt][t][sg * 4 + j] = make_float2((&pb1.x)[j], (&pc1.x)[j]);
            }
            dsh[nxt][st_t][st_d] = pd;
        }
        __syncthreads();   // T + next buf visible to all

        // coalesced y_row write from T
        {
            float v = T[st_t * 9 + st_d];
            y_row[(size_t)(r0 + st_t) * DI + dg * 8 + st_d] = __float2bfloat16(v);
        }

        xv = nxv; zv = nzv;
    }
}

extern "C" void kernel_launch(void* const* d_in, const int* in_sizes, int n_in,
                              void* d_out, int out_size, void* d_ws, size_t ws_size,
                              hipStream_t stream) {
    const float* frames = (const float*)d_in[0];
    const float* gamma  = (const float*)d_in[1];
    const float* beta   = (const float*)d_in[2];
    const float* W_in   = (const float*)d_in[3];
    const float* conv_w = (const float*)d_in[4];
    const float* conv_b = (const float*)d_in[5];
    const float* W_x    = (const float*)d_in[6];
    const float* W_dt   = (const float*)d_in[7];
    const float* b_dt   = (const float*)d_in[8];
    const float* A_log  = (const float*)d_in[9];
    const float* Dp     = (const float*)d_in[10];
    const float* W_out  = (const float*)d_in[11];
    float* out = (float*)d_out;

    // workspace carve-up (bytes)
    char* ws = (char*)d_ws;
    __hip_bfloat16* xn_bf  = (__hip_bfloat16*)ws; ws += (size_t)NROWS * DM * 2;
    __hip_bfloat16* Wt_in  = (__hip_bfloat16*)ws; ws += (size_t)(2 * DI) * DM * 2;
    __hip_bfloat16* Wt_out = (__hip_bfloat16*)ws; ws += (size_t)DM * DI * 2;
    __hip_bfloat16* Wt_x   = (__hip_bfloat16*)ws; ws += (size_t)XDBW * DI * 2;
    __hip_bfloat16* y_row  = (__hip_bfloat16*)ws; ws += (size_t)NROWS * DI * 2;
    __hip_bfloat16* xcv_bf = (__hip_bfloat16*)ws; ws += (size_t)NROWS * DI * 2;
    __hip_bfloat16* xh     = (__hip_bfloat16*)ws; ws += (size_t)NROWS * DI * 2;
    __hip_bfloat16* zh     = (__hip_bfloat16*)ws; ws += (size_t)NROWS * DI * 2;
    __hip_bfloat16* xcvT   = (__hip_bfloat16*)ws; ws += (size_t)NROWS * DI * 2;
    __hip_bfloat16* zgT    = (__hip_bfloat16*)ws; ws += (size_t)NROWS * DI * 2;
    float* xdb    = (float*)ws;  ws += (size_t)NROWS * XDBW * 4;
    float* delta  = (float*)ws;  ws += (size_t)NROWS * DI * 4;

    // fused LN + weight transposes
    prep_kernel<<<NROWS + 432, 256, 0, stream>>>(frames, gamma, beta, W_in, W_out, W_x,
                                                 xn_bf, Wt_in, Wt_out, Wt_x);

    // in_proj -> bf16 x-half / z-half (BK=64)
    gemm_inproj<<<dim3(2 * DI / 128, NROWS / 128), 512, 0, stream>>>(
        xn_bf, Wt_in, xh, zh, NROWS, 2 * DI, DM);

    // conv + silu + transposes
    conv_tile<<<dim3(Lseq / 64, DI / 64, Bn), 256, 0, stream>>>(
        xh, zh, conv_w, conv_b, xcv_bf, xcvT, zgT);

    // xdb = xcv @ W_x  (M=2048, N=160, K=1024, BK=64 split-K)
    gemm64_sk<false><<<dim3((XDBW + 63) / 64, NROWS / 64), 512, 0, stream>>>(
        xcv_bf, Wt_x, nullptr, xdb, NROWS, XDBW, DI);

    delta_kernel<<<dim3(DI / 256, NROWS / DROWS), 256, 0, stream>>>(xdb, W_dt, b_dt, delta);

    // single-pass serial selective scan
    scan_full<<<Bn * (DI / 8), 512, 0, stream>>>(delta, xcvT, xdb, zgT, A_log, Dp, y_row);

    // out_proj: out = y_row @ W_out + frames (BK=64 split-K)
    gemm64_sk<true><<<dim3(DM / 64, NROWS / 64), 512, 0, stream>>>(
        y_row, Wt_out, frames, out, NROWS, DM, DI);
}

// Round 10
// 220.183 us; speedup vs baseline: 1.1028x; 1.0141x over previous
//
#include <hip/hip_runtime.h>
#include <hip/hip_bf16.h>
#include <math.h>

// Problem constants
constexpr int Bn     = 2;
constexpr int Lseq   = 1024;
constexpr int DM     = 512;    // d_model
constexpr int DI     = 1024;   // d_inner
constexpr int DS     = 64;     // d_state
constexpr int RNK    = 32;     // dt_rank
constexpr int NROWS  = Bn * Lseq;  // 2048
constexpr int XDBW   = RNK + 2 * DS; // 160
constexpr int CH     = 64;     // scan tile length
constexpr int NC     = Lseq / CH;  // 16 tiles
constexpr int DROWS  = 8;      // delta kernel rows per block

constexpr float LOG2E = 1.44269504088896340736f;

typedef __attribute__((ext_vector_type(4))) float floatx4;
typedef __attribute__((ext_vector_type(8))) short shortx8;

__device__ __forceinline__ float silu_f(float v) {
    return v / (1.f + __expf(-v));
}

__device__ __forceinline__ float rdl(float v, int l) {
    return __int_as_float(__builtin_amdgcn_readlane(__float_as_int(v), l));
}

__device__ __forceinline__ float bf2f(unsigned short u) {
    return __uint_as_float((unsigned)u << 16);
}

// exp2 that maps straight to v_exp_f32 (no hidden ×log2e mul)
__device__ __forceinline__ float exp2_fast(float x) {
#if __has_builtin(__builtin_amdgcn_exp2f)
    return __builtin_amdgcn_exp2f(x);
#else
    return exp2f(x);
#endif
}

// ---------------- Fused prep: LN (blocks 0..2047) + 3 weight transposes (2048..2479) ----
__global__ void prep_kernel(const float* __restrict__ x, const float* __restrict__ g,
                            const float* __restrict__ be,
                            const float* __restrict__ Wi, const float* __restrict__ Wo,
                            const float* __restrict__ Wx,
                            __hip_bfloat16* __restrict__ xn,
                            __hip_bfloat16* __restrict__ Ti, __hip_bfloat16* __restrict__ To,
                            __hip_bfloat16* __restrict__ Tx) {
    __shared__ float tile[64][65];
    __shared__ float red[8];
    int bid = blockIdx.x;
    int tid = threadIdx.x;
    if (bid < NROWS) {
        int row = bid;
        const float* xr = x + (size_t)row * DM;
        float v0 = xr[tid], v1 = xr[tid + 256];
        float s = v0 + v1, sq = v0 * v0 + v1 * v1;
        #pragma unroll
        for (int o = 1; o < 64; o <<= 1) {
            s  += __shfl_xor(s, o);
            sq += __shfl_xor(sq, o);
        }
        int w = tid >> 6;
        if ((tid & 63) == 0) { red[w] = s; red[4 + w] = sq; }
        __syncthreads();
        float ts = red[0] + red[1] + red[2] + red[3];
        float tq = red[4] + red[5] + red[6] + red[7];
        float mu  = ts * (1.f / DM);
        float var = tq * (1.f / DM) - mu * mu;
        float inv = rsqrtf(var + 1e-5f);
        __hip_bfloat16* o0 = xn + (size_t)row * DM;
        o0[tid]       = __float2bfloat16((v0 - mu) * inv * g[tid]       + be[tid]);
        o0[tid + 256] = __float2bfloat16((v1 - mu) * inv * g[tid + 256] + be[tid + 256]);
        return;
    }
    int b2 = bid - NROWS;
    const float* in; __hip_bfloat16* out; int R, Cc, bx, by;
    if (b2 < 256)      { in = Wi; out = Ti; R = DM; Cc = 2 * DI; bx = b2 & 31; by = b2 >> 5; }
    else if (b2 < 384) { int b3 = b2 - 256; in = Wo; out = To; R = DI; Cc = DM;   bx = b3 & 7; by = b3 >> 3; }
    else               { int b3 = b2 - 384; in = Wx; out = Tx; R = DI; Cc = XDBW; bx = b3 % 3; by = b3 / 3; }
    int r0 = by * 64, c0 = bx * 64;
    #pragma unroll
    for (int i = tid; i < 4096; i += 256) {
        int r = i >> 6, c = i & 63;
        tile[r][c] = (r0 + r < R && c0 + c < Cc) ? in[(size_t)(r0 + r) * Cc + c0 + c] : 0.f;
    }
    __syncthreads();
    #pragma unroll
    for (int i = tid; i < 4096; i += 256) {
        int c = i >> 6, r = i & 63;
        if (r0 + r < R && c0 + c < Cc)
            out[(size_t)(c0 + c) * R + r0 + r] = __float2bfloat16(tile[r][c]);
    }
}

// ---------------- in_proj GEMM 128x128 tile, 512 thr, BK=64 (2 stacked 32-K panels) -----
__global__ __launch_bounds__(512) void gemm_inproj(const __hip_bfloat16* __restrict__ A,
                                                   const __hip_bfloat16* __restrict__ Bt,
                                                   __hip_bfloat16* __restrict__ xh,
                                                   __hip_bfloat16* __restrict__ zh,
                                                   int M, int N, int K) {
    __shared__ __hip_bfloat16 As[128 * 64];
    __shared__ __hip_bfloat16 Bs[128 * 64];
    const int tid  = threadIdx.x;
    const int wave = tid >> 6, lane = tid & 63;
    const int m0 = blockIdx.y * 128, n0 = blockIdx.x * 128;
    const int wm = (wave >> 2) * 64, wn = (wave & 3) * 32;

    floatx4 acc[4][2] = {};

    const int arow16 = lane & 15;
    const int kgrp   = lane >> 4;

    for (int k0 = 0; k0 < K; k0 += 64) {
        #pragma unroll
        for (int p = 0; p < 2; ++p) {
            int j = tid + p * 512;            // 0..1023 chunk index
            int h = j >> 9, rs = j & 511;
            int row = rs >> 2, seg = rs & 3;
            const __hip_bfloat16* gA = A  + (size_t)(m0 + row) * K + k0 + h * 32 + seg * 8;
            const __hip_bfloat16* gB = Bt + (size_t)(n0 + row) * K + k0 + h * 32 + seg * 8;
            __hip_bfloat16* lA = As + (size_t)(wave * 64 + p * 512) * 8;
            __hip_bfloat16* lB = Bs + (size_t)(wave * 64 + p * 512) * 8;
            __builtin_amdgcn_global_load_lds(
                (const __attribute__((address_space(1))) void*)gA,
                (__attribute__((address_space(3))) void*)lA, 16, 0, 0);
            __builtin_amdgcn_global_load_lds(
                (const __attribute__((address_space(1))) void*)gB,
                (__attribute__((address_space(3))) void*)lB, 16, 0, 0);
        }
        __syncthreads();

        const shortx8* Asv = (const shortx8*)As;
        const shortx8* Bsv = (const shortx8*)Bs;
        #pragma unroll
        for (int h = 0; h < 2; ++h) {
            shortx8 a[4], b[2];
            #pragma unroll
            for (int i = 0; i < 4; ++i)
                a[i] = Asv[h * 512 + (wm + i * 16 + arow16) * 4 + kgrp];
            #pragma unroll
            for (int j = 0; j < 2; ++j)
                b[j] = Bsv[h * 512 + (wn + j * 16 + arow16) * 4 + kgrp];
            #pragma unroll
            for (int i = 0; i < 4; ++i)
                #pragma unroll
                for (int j = 0; j < 2; ++j)
                    acc[i][j] = __builtin_amdgcn_mfma_f32_16x16x32_bf16(a[i], b[j], acc[i][j], 0, 0, 0);
        }
        __syncthreads();
    }

    const int drow = (lane >> 4) * 4;
    const int dcol = lane & 15;
    const bool isz = (n0 >= DI);
    __hip_bfloat16* dst = isz ? zh : xh;
    const int coloff = isz ? DI : 0;
    #pragma unroll
    for (int i = 0; i < 4; ++i)
        #pragma unroll
        for (int j = 0; j < 2; ++j) {
            int rowb = m0 + wm + i * 16 + drow;
            int col  = n0 + wn + j * 16 + dcol - coloff;
            #pragma unroll
            for (int r = 0; r < 4; ++r)
                dst[(size_t)(rowb + r) * DI + col] = __float2bfloat16(acc[i][j][r]);
        }
}

// ---------------- bf16 MFMA GEMM 64x64 tile, 512 thr, split-K, BK=64 (2 panels) ---------
template<bool RES>
__global__ __launch_bounds__(512) void gemm64_sk(const __hip_bfloat16* __restrict__ A,
                                                 const __hip_bfloat16* __restrict__ Bt,
                                                 const float* __restrict__ Res,
                                                 float* __restrict__ C,
                                                 int M, int N, int K) {
    __shared__ __hip_bfloat16 As[2][64 * 64];
    __shared__ __hip_bfloat16 Bs[2][64 * 64];
    __shared__ float red[256 * 17];
    const int tid  = threadIdx.x;
    const int wave = tid >> 6, lane = tid & 63;
    const int g = wave >> 2, w2 = wave & 3;
    const int m0 = blockIdx.y * 64, n0 = blockIdx.x * 64;
    const int wm = (w2 >> 1) * 32, wn = (w2 & 1) * 32;

    floatx4 acc[2][2] = {};

    const int arow16 = lane & 15;
    const int kgrp   = lane >> 4;
    const int kbeg   = g * (K / 2);

    for (int kk = 0; kk < K / 2; kk += 64) {
        int k0 = kbeg + kk;
        #pragma unroll
        for (int p = 0; p < 2; ++p) {
            int j = (w2 * 64 + lane) + p * 256;   // 0..511 chunk index within group
            int h = j >> 8, rs = j & 255;
            int row = rs >> 2, seg = rs & 3;
            int brow = n0 + row; if (brow >= N) brow = N - 1;
            const __hip_bfloat16* gA = A  + (size_t)(m0 + row) * K + k0 + h * 32 + seg * 8;
            const __hip_bfloat16* gB = Bt + (size_t)brow * K + k0 + h * 32 + seg * 8;
            __hip_bfloat16* lA = As[g] + (size_t)(w2 * 64 + p * 256) * 8;
            __hip_bfloat16* lB = Bs[g] + (size_t)(w2 * 64 + p * 256) * 8;
            __builtin_amdgcn_global_load_lds(
                (const __attribute__((address_space(1))) void*)gA,
                (__attribute__((address_space(3))) void*)lA, 16, 0, 0);
            __builtin_amdgcn_global_load_lds(
                (const __attribute__((address_space(1))) void*)gB,
                (__attribute__((address_space(3))) void*)lB, 16, 0, 0);
        }
        __syncthreads();

        const shortx8* Asv = (const shortx8*)As[g];
        const shortx8* Bsv = (const shortx8*)Bs[g];
        #pragma unroll
        for (int h = 0; h < 2; ++h) {
            shortx8 a[2], b[2];
            #pragma unroll
            for (int i = 0; i < 2; ++i)
                a[i] = Asv[h * 256 + (wm + i * 16 + arow16) * 4 + kgrp];
            #pragma unroll
            for (int j = 0; j < 2; ++j)
                b[j] = Bsv[h * 256 + (wn + j * 16 + arow16) * 4 + kgrp];
            #pragma unroll
            for (int i = 0; i < 2; ++i)
                #pragma unroll
                for (int j = 0; j < 2; ++j)
                    acc[i][j] = __builtin_amdgcn_mfma_f32_16x16x32_bf16(a[i], b[j], acc[i][j], 0, 0, 0);
        }
        __syncthreads();
    }

    int rbase = (w2 * 64 + lane) * 17;
    if (g == 1) {
        #pragma unroll
        for (int i = 0; i < 2; ++i)
            #pragma unroll
            for (int j = 0; j < 2; ++j)
                *(float4*)&red[rbase + (i * 2 + j) * 4] =
                    make_float4(acc[i][j][0], acc[i][j][1], acc[i][j][2], acc[i][j][3]);
    }
    __syncthreads();
    if (g == 0) {
        const int drow = (lane >> 4) * 4;
        const int dcol = lane & 15;
        #pragma unroll
        for (int i = 0; i < 2; ++i)
            #pragma unroll
            for (int j = 0; j < 2; ++j) {
                float4 part = *(const float4*)&red[rbase + (i * 2 + j) * 4];
                int rowb = m0 + wm + i * 16 + drow;
                int col  = n0 + wn + j * 16 + dcol;
                if (col < N) {
                    #pragma unroll
                    for (int r = 0; r < 4; ++r) {
                        size_t idx = (size_t)(rowb + r) * N + col;
                        float v = acc[i][j][r] + (&part.x)[r];
                        if (RES) v += Res[idx];
                        C[idx] = v;
                    }
                }
            }
    }
}

// ---------------- Tiled conv + silu + transposes ----------------
__global__ __launch_bounds__(256) void conv_tile(const __hip_bfloat16* __restrict__ xh,
                                                 const __hip_bfloat16* __restrict__ zh,
                                                 const float* __restrict__ cw,
                                                 const float* __restrict__ cb,
                                                 __hip_bfloat16* __restrict__ xcv_bf,
                                                 __hip_bfloat16* __restrict__ xcvT,
                                                 __hip_bfloat16* __restrict__ zgT) {
    __shared__ float xt[67][68];
    __shared__ float tb[64][65];    // conv+silu result [t][d]
    __shared__ float tb2[64][65];   // silu(z) [t][d]
    int t0 = blockIdx.x * 64, d0 = blockIdx.y * 64, b = blockIdx.z;
    int tid = threadIdx.x;
    size_t rowbase = (size_t)b * Lseq;

    for (int i = tid; i < 67 * 16; i += 256) {
        int r = i >> 4, j = i & 15;
        int t = t0 - 3 + r;
        float4 v4 = make_float4(0.f, 0.f, 0.f, 0.f);
        if (t >= 0) {
            ushort4 u = *(const ushort4*)&xh[(rowbase + t) * DI + d0 + j * 4];
            v4 = make_float4(bf2f(u.x), bf2f(u.y), bf2f(u.z), bf2f(u.w));
        }
        *(float4*)&xt[r][j * 4] = v4;
    }
    for (int i = tid; i < 64 * 16; i += 256) {
        int r = i >> 4, j = i & 15;
        ushort4 u = *(const ushort4*)&zh[(rowbase + t0 + r) * DI + d0 + j * 4];
        tb2[r][j * 4 + 0] = silu_f(bf2f(u.x));
        tb2[r][j * 4 + 1] = silu_f(bf2f(u.y));
        tb2[r][j * 4 + 2] = silu_f(bf2f(u.z));
        tb2[r][j * 4 + 3] = silu_f(bf2f(u.w));
    }
    __syncthreads();

    {
        int d = tid & 63, tg = tid >> 6;
        float4 cwv = *(const float4*)&cw[(d0 + d) * 4];
        float cbv = cb[d0 + d];
        #pragma unroll
        for (int i = 0; i < 16; ++i) {
            int t = tg * 16 + i;
            float acc = cbv;
            #pragma unroll
            for (int k = 0; k < 4; ++k) acc += xt[t + k][d] * (&cwv.x)[k];
            float v = silu_f(acc);
            tb[t][d] = v;
            xcv_bf[(rowbase + t0 + t) * DI + d0 + d] = __float2bfloat16(v);
        }
    }
    __syncthreads();

    {
        int t2 = tid & 63, dg2 = tid >> 6;
        #pragma unroll
        for (int i = 0; i < 16; ++i) {
            int d = dg2 * 16 + i;
            size_t orow = ((size_t)(b * DI + d0 + d)) * Lseq + t0 + t2;
            xcvT[orow] = __float2bfloat16(tb[t2][d]);
            zgT[orow]  = __float2bfloat16(tb2[t2][d]);
        }
    }
}

// ---------------- delta = softplus(dt @ W_dt + b_dt), 8 rows per block ----------------
__global__ __launch_bounds__(256) void delta_kernel(const float* __restrict__ xdb,
                                                    const float* __restrict__ Wdt,
                                                    const float* __restrict__ bdt,
                                                    float* __restrict__ delta) {
    int r0 = blockIdx.y * DROWS;
    int d = blockIdx.x * 256 + threadIdx.x;
    __shared__ float dtv[RNK][DROWS];   // [r][k] -> wave-uniform b128 reads
    if (threadIdx.x < DROWS * RNK) {
        int k = threadIdx.x >> 5, r = threadIdx.x & 31;
        dtv[r][k] = xdb[(size_t)(r0 + k) * XDBW + r];
    }
    __syncthreads();
    float bb = bdt[d];
    float acc[DROWS];
    #pragma unroll
    for (int k = 0; k < DROWS; ++k) acc[k] = bb;
    #pragma unroll
    for (int r = 0; r < RNK; ++r) {
        float wv = Wdt[(size_t)r * DI + d];
        float4 lo = *(const float4*)&dtv[r][0];
        float4 hi = *(const float4*)&dtv[r][4];
        acc[0] += lo.x * wv; acc[1] += lo.y * wv;
        acc[2] += lo.z * wv; acc[3] += lo.w * wv;
        acc[4] += hi.x * wv; acc[5] += hi.y * wv;
        acc[6] += hi.z * wv; acc[7] += hi.w * wv;
    }
    #pragma unroll
    for (int k = 0; k < DROWS; ++k) {
        float a = acc[k];
        float sp = (a > 20.f) ? a : log1pf(__expf(a));
        delta[(size_t)(r0 + k) * DI + d] = sp;
    }
}

// ============ Single-pass serial scan: B/C via DIRECT coalesced global loads ============
// 1 channel/wave, h across all 16 tiles. Per t, lane s reads B_t[s]/C_t[s] straight
// from xdb (consecutive floats -> one coalesced 256B load; all 8 waves hit the same
// L1 line). This moves the dominant LDS-pipe traffic (BC staging + reads, ~2 of 4.4
// LDS ops/t, round-7 kernel was LDS-issue-bound at VALUBusy 44%) onto the idle
// L1/VMEM path. Loads software-pipelined one 16-t group ahead (2 register sets,
// even group count -> carry consistent across tiles). LDS keeps only dsh/P/T
// (proven conflict-free). Same f32 values, same op order as v7 -> bit-exact.
__global__ __launch_bounds__(512) void scan_full(
        const float* __restrict__ delta, const __hip_bfloat16* __restrict__ xcvT,
        const float* __restrict__ xdb, const __hip_bfloat16* __restrict__ zgT,
        const float* __restrict__ A_log, const float* __restrict__ Dp,
        __hip_bfloat16* __restrict__ y_row) {
    __shared__ float dsh[2][64][9];    // [buf][t][ch] delta staging
    __shared__ float P[8][8 * 65];     // per-wave reduce scratch, odd stride 65
    __shared__ float T[64 * 9];        // y transpose staging [t][ch]

    int blk = blockIdx.x;              // Bn * DI/8 = 256
    int dg  = blk & 127;               // DI/8 = 128
    int b   = blk >> 7;
    int tid = threadIdx.x, w = tid >> 6, lane = tid & 63;
    int d = dg * 8 + w;

    float a2 = -__expf(A_log[d * DS + lane]) * LOG2E;  // exp(x) == exp2(x*log2e)
    float Dv = Dp[d];

    const int st_t = tid >> 3, st_d = tid & 7;

    // stage tile-0 delta
    dsh[0][st_t][st_d] = delta[(size_t)(b * Lseq + st_t) * DI + dg * 8 + st_d];
    __syncthreads();

    const unsigned short* xT = (const unsigned short*)xcvT;
    const unsigned short* zT = (const unsigned short*)zgT;
    const size_t chbase = (size_t)(b * DI + d) * Lseq;

    float xv = bf2f(xT[chbase + lane]);   // tile 0 x/z prefetched
    float zv = bf2f(zT[chbase + lane]);

    float h = 0.f;
    float* Pw = P[w];
    const int tr = lane & 7, q = lane >> 3;
    const int rdbase = tr * 65 + q * 8;

    // per-lane B/C column pointers: B_t[lane] = Bcol[t*XDBW] (coalesced across lanes)
    const float* Bcol = xdb + RNK + lane;
    const float* Ccol = xdb + RNK + DS + lane;

    // preload group 0 of tile 0 into set A (groups of 16 t; 4 groups/tile)
    float bA[16], cA[16], bB[16], cB[16];
    #pragma unroll
    for (int k = 0; k < 16; ++k) {
        bA[k] = Bcol[(size_t)(b * Lseq + k) * XDBW];
        cA[k] = Ccol[(size_t)(b * Lseq + k) * XDBW];
    }

    for (int c = 0; c < NC; ++c) {
        int cur = c & 1;

        // tile-level prefetch (x, z, delta for tile c+1)
        float pd = 0.f, nxv = 0.f, nzv = 0.f;
        if (c + 1 < NC) {
            int r1 = b * Lseq + (c + 1) * CH;
            pd  = delta[(size_t)(r1 + st_t) * DI + dg * 8 + st_d];
            nxv = bf2f(xT[chbase + (c + 1) * CH + lane]);
            nzv = bf2f(zT[chbase + (c + 1) * CH + lane]);
        }

        int r0 = b * Lseq + c * CH;
        int rnext = (c + 1 < NC) ? (r0 + CH) : r0;   // clamped: last tile reloads valid addrs

        float vd  = dsh[cur][lane][w];   // delta_t for t = lane
        float vpx = vd * xv;             // delta_t * x_t
        float y = 0.f;

        #pragma unroll
        for (int g4 = 0; g4 < 4; ++g4) {
            // issue next-group loads into the other register set (hoisted above chain)
            int rg = (g4 < 3) ? (r0 + (g4 + 1) * 16) : rnext;
            if ((g4 & 1) == 0) {
                #pragma unroll
                for (int k = 0; k < 16; ++k) {
                    bB[k] = Bcol[(size_t)(rg + k) * XDBW];
                    cB[k] = Ccol[(size_t)(rg + k) * XDBW];
                }
            } else {
                #pragma unroll
                for (int k = 0; k < 16; ++k) {
                    bA[k] = Bcol[(size_t)(rg + k) * XDBW];
                    cA[k] = Ccol[(size_t)(rg + k) * XDBW];
                }
            }
            // compute this group's 16 t (two 8-t reduce sub-chunks)
            #pragma unroll
            for (int half = 0; half < 2; ++half) {
                #pragma unroll
                for (int kk = 0; kk < 8; ++kk) {
                    int k = half * 8 + kk;
                    int t = g4 * 16 + k;
                    float Bv = ((g4 & 1) == 0) ? bA[k] : bB[k];
                    float Cv = ((g4 & 1) == 0) ? cA[k] : cB[k];
                    h = h * exp2_fast(rdl(vd, t) * a2) + rdl(vpx, t) * Bv;
                    Pw[kk * 65 + lane] = h * Cv;
                }
                float sacc = 0.f;
                #pragma unroll
                for (int j = 0; j < 8; ++j) sacc += Pw[rdbase + j];
                sacc += __shfl_xor(sacc, 8);
                sacc += __shfl_xor(sacc, 16);
                sacc += __shfl_xor(sacc, 32);
                int t8 = g4 * 2 + half;
                if (q == t8) y = sacc;   // lane l ends with y for t = l
            }
        }

        float yv = (y + xv * Dv) * zv;

        __syncthreads();   // all waves done with prior tile's T reads
        T[lane * 9 + w] = yv;
        if (c + 1 < NC) dsh[cur ^ 1][st_t][st_d] = pd;
        __syncthreads();   // T + next dsh visible to all

        // coalesced y_row write from T
        {
            float v = T[st_t * 9 + st_d];
            y_row[(size_t)(r0 + st_t) * DI + dg * 8 + st_d] = __float2bfloat16(v);
        }

        xv = nxv; zv = nzv;
    }
}

extern "C" void kernel_launch(void* const* d_in, const int* in_sizes, int n_in,
                              void* d_out, int out_size, void* d_ws, size_t ws_size,
                              hipStream_t stream) {
    const float* frames = (const float*)d_in[0];
    const float* gamma  = (const float*)d_in[1];
    const float* beta   = (const float*)d_in[2];
    const float* W_in   = (const float*)d_in[3];
    const float* conv_w = (const float*)d_in[4];
    const float* conv_b = (const float*)d_in[5];
    const float* W_x    = (const float*)d_in[6];
    const float* W_dt   = (const float*)d_in[7];
    const float* b_dt   = (const float*)d_in[8];
    const float* A_log  = (const float*)d_in[9];
    const float* Dp     = (const float*)d_in[10];
    const float* W_out  = (const float*)d_in[11];
    float* out = (float*)d_out;

    // workspace carve-up (bytes)
    char* ws = (char*)d_ws;
    __hip_bfloat16* xn_bf  = (__hip_bfloat16*)ws; ws += (size_t)NROWS * DM * 2;
    __hip_bfloat16* Wt_in  = (__hip_bfloat16*)ws; ws += (size_t)(2 * DI) * DM * 2;
    __hip_bfloat16* Wt_out = (__hip_bfloat16*)ws; ws += (size_t)DM * DI * 2;
    __hip_bfloat16* Wt_x   = (__hip_bfloat16*)ws; ws += (size_t)XDBW * DI * 2;
    __hip_bfloat16* y_row  = (__hip_bfloat16*)ws; ws += (size_t)NROWS * DI * 2;
    __hip_bfloat16* xcv_bf = (__hip_bfloat16*)ws; ws += (size_t)NROWS * DI * 2;
    __hip_bfloat16* xh     = (__hip_bfloat16*)ws; ws += (size_t)NROWS * DI * 2;
    __hip_bfloat16* zh     = (__hip_bfloat16*)ws; ws += (size_t)NROWS * DI * 2;
    __hip_bfloat16* xcvT   = (__hip_bfloat16*)ws; ws += (size_t)NROWS * DI * 2;
    __hip_bfloat16* zgT    = (__hip_bfloat16*)ws; ws += (size_t)NROWS * DI * 2;
    float* xdb    = (float*)ws;  ws += (size_t)NROWS * XDBW * 4;
    float* delta  = (float*)ws;  ws += (size_t)NROWS * DI * 4;

    // fused LN + weight transposes
    prep_kernel<<<NROWS + 432, 256, 0, stream>>>(frames, gamma, beta, W_in, W_out, W_x,
                                                 xn_bf, Wt_in, Wt_out, Wt_x);

    // in_proj -> bf16 x-half / z-half (BK=64)
    gemm_inproj<<<dim3(2 * DI / 128, NROWS / 128), 512, 0, stream>>>(
        xn_bf, Wt_in, xh, zh, NROWS, 2 * DI, DM);

    // conv + silu + transposes
    conv_tile<<<dim3(Lseq / 64, DI / 64, Bn), 256, 0, stream>>>(
        xh, zh, conv_w, conv_b, xcv_bf, xcvT, zgT);

    // xdb = xcv @ W_x  (M=2048, N=160, K=1024, BK=64 split-K)
    gemm64_sk<false><<<dim3((XDBW + 63) / 64, NROWS / 64), 512, 0, stream>>>(
        xcv_bf, Wt_x, nullptr, xdb, NROWS, XDBW, DI);

    delta_kernel<<<dim3(DI / 256, NROWS / DROWS), 256, 0, stream>>>(xdb, W_dt, b_dt, delta);

    // single-pass serial selective scan
    scan_full<<<Bn * (DI / 8), 512, 0, stream>>>(delta, xcvT, xdb, zgT, A_log, Dp, y_row);

    // out_proj: out = y_row @ W_out + frames (BK=64 split-K)
    gemm64_sk<true><<<dim3(DM / 64, NROWS / 64), 512, 0, stream>>>(
        y_row, Wt_out, frames, out, NROWS, DM, DI);
}

// Round 11
// 218.096 us; speedup vs baseline: 1.1134x; 1.0096x over previous
//
#include <hip/hip_runtime.h>
#include <hip/hip_bf16.h>
#include <math.h>

// Problem constants
constexpr int Bn     = 2;
constexpr int Lseq   = 1024;
constexpr int DM     = 512;    // d_model
constexpr int DI     = 1024;   // d_inner
constexpr int DS     = 64;     // d_state
constexpr int RNK    = 32;     // dt_rank
constexpr int NROWS  = Bn * Lseq;  // 2048
constexpr int XDBW   = RNK + 2 * DS; // 160
constexpr int CH     = 64;     // scan tile length
constexpr int NC     = Lseq / CH;  // 16 tiles
constexpr int DROWS  = 8;      // delta kernel rows per block

constexpr float LOG2E = 1.44269504088896340736f;

typedef __attribute__((ext_vector_type(4))) float floatx4;
typedef __attribute__((ext_vector_type(8))) short shortx8;

__device__ __forceinline__ float silu_f(float v) {
    return v / (1.f + __expf(-v));
}

__device__ __forceinline__ float rdl(float v, int l) {
    return __int_as_float(__builtin_amdgcn_readlane(__float_as_int(v), l));
}

__device__ __forceinline__ float bf2f(unsigned short u) {
    return __uint_as_float((unsigned)u << 16);
}

// exp2 that maps straight to v_exp_f32 (no hidden ×log2e mul)
__device__ __forceinline__ float exp2_fast(float x) {
#if __has_builtin(__builtin_amdgcn_exp2f)
    return __builtin_amdgcn_exp2f(x);
#else
    return exp2f(x);
#endif
}

// v += row_ror:N(v) within 16-lane rows — pure-VALU cross-lane add (DPP), no LDS.
// After N=1,2,4,8 every lane of a 16-lane row holds the row's full sum.
template<int N>
__device__ __forceinline__ float ror_add16(float v) {
    int r = __builtin_amdgcn_update_dpp(0, __float_as_int(v), 0x120 | N, 0xF, 0xF, false);
    return v + __int_as_float(r);
}

// lane that carries the recurrence values for tile-local t (inverse of tmap)
__device__ __forceinline__ constexpr int invl(int t) { return 16 * (t & 3) + (t >> 2); }

// ---------------- Fused prep: LN (blocks 0..2047) + 3 weight transposes (2048..2479) ----
__global__ void prep_kernel(const float* __restrict__ x, const float* __restrict__ g,
                            const float* __restrict__ be,
                            const float* __restrict__ Wi, const float* __restrict__ Wo,
                            const float* __restrict__ Wx,
                            __hip_bfloat16* __restrict__ xn,
                            __hip_bfloat16* __restrict__ Ti, __hip_bfloat16* __restrict__ To,
                            __hip_bfloat16* __restrict__ Tx) {
    __shared__ float tile[64][65];
    __shared__ float red[8];
    int bid = blockIdx.x;
    int tid = threadIdx.x;
    if (bid < NROWS) {
        int row = bid;
        const float* xr = x + (size_t)row * DM;
        float v0 = xr[tid], v1 = xr[tid + 256];
        float s = v0 + v1, sq = v0 * v0 + v1 * v1;
        #pragma unroll
        for (int o = 1; o < 64; o <<= 1) {
            s  += __shfl_xor(s, o);
            sq += __shfl_xor(sq, o);
        }
        int w = tid >> 6;
        if ((tid & 63) == 0) { red[w] = s; red[4 + w] = sq; }
        __syncthreads();
        float ts = red[0] + red[1] + red[2] + red[3];
        float tq = red[4] + red[5] + red[6] + red[7];
        float mu  = ts * (1.f / DM);
        float var = tq * (1.f / DM) - mu * mu;
        float inv = rsqrtf(var + 1e-5f);
        __hip_bfloat16* o0 = xn + (size_t)row * DM;
        o0[tid]       = __float2bfloat16((v0 - mu) * inv * g[tid]       + be[tid]);
        o0[tid + 256] = __float2bfloat16((v1 - mu) * inv * g[tid + 256] + be[tid + 256]);
        return;
    }
    int b2 = bid - NROWS;
    const float* in; __hip_bfloat16* out; int R, Cc, bx, by;
    if (b2 < 256)      { in = Wi; out = Ti; R = DM; Cc = 2 * DI; bx = b2 & 31; by = b2 >> 5; }
    else if (b2 < 384) { int b3 = b2 - 256; in = Wo; out = To; R = DI; Cc = DM;   bx = b3 & 7; by = b3 >> 3; }
    else               { int b3 = b2 - 384; in = Wx; out = Tx; R = DI; Cc = XDBW; bx = b3 % 3; by = b3 / 3; }
    int r0 = by * 64, c0 = bx * 64;
    #pragma unroll
    for (int i = tid; i < 4096; i += 256) {
        int r = i >> 6, c = i & 63;
        tile[r][c] = (r0 + r < R && c0 + c < Cc) ? in[(size_t)(r0 + r) * Cc + c0 + c] : 0.f;
    }
    __syncthreads();
    #pragma unroll
    for (int i = tid; i < 4096; i += 256) {
        int c = i >> 6, r = i & 63;
        if (r0 + r < R && c0 + c < Cc)
            out[(size_t)(c0 + c) * R + r0 + r] = __float2bfloat16(tile[r][c]);
    }
}

// ---------------- in_proj GEMM 128x128 tile, 512 thr, BK=64 (2 stacked 32-K panels) -----
__global__ __launch_bounds__(512) void gemm_inproj(const __hip_bfloat16* __restrict__ A,
                                                   const __hip_bfloat16* __restrict__ Bt,
                                                   __hip_bfloat16* __restrict__ xh,
                                                   __hip_bfloat16* __restrict__ zh,
                                                   int M, int N, int K) {
    __shared__ __hip_bfloat16 As[128 * 64];
    __shared__ __hip_bfloat16 Bs[128 * 64];
    const int tid  = threadIdx.x;
    const int wave = tid >> 6, lane = tid & 63;
    const int m0 = blockIdx.y * 128, n0 = blockIdx.x * 128;
    const int wm = (wave >> 2) * 64, wn = (wave & 3) * 32;

    floatx4 acc[4][2] = {};

    const int arow16 = lane & 15;
    const int kgrp   = lane >> 4;

    for (int k0 = 0; k0 < K; k0 += 64) {
        #pragma unroll
        for (int p = 0; p < 2; ++p) {
            int j = tid + p * 512;            // 0..1023 chunk index
            int h = j >> 9, rs = j & 511;
            int row = rs >> 2, seg = rs & 3;
            const __hip_bfloat16* gA = A  + (size_t)(m0 + row) * K + k0 + h * 32 + seg * 8;
            const __hip_bfloat16* gB = Bt + (size_t)(n0 + row) * K + k0 + h * 32 + seg * 8;
            __hip_bfloat16* lA = As + (size_t)(wave * 64 + p * 512) * 8;
            __hip_bfloat16* lB = Bs + (size_t)(wave * 64 + p * 512) * 8;
            __builtin_amdgcn_global_load_lds(
                (const __attribute__((address_space(1))) void*)gA,
                (__attribute__((address_space(3))) void*)lA, 16, 0, 0);
            __builtin_amdgcn_global_load_lds(
                (const __attribute__((address_space(1))) void*)gB,
                (__attribute__((address_space(3))) void*)lB, 16, 0, 0);
        }
        __syncthreads();

        const shortx8* Asv = (const shortx8*)As;
        const shortx8* Bsv = (const shortx8*)Bs;
        #pragma unroll
        for (int h = 0; h < 2; ++h) {
            shortx8 a[4], b[2];
            #pragma unroll
            for (int i = 0; i < 4; ++i)
                a[i] = Asv[h * 512 + (wm + i * 16 + arow16) * 4 + kgrp];
            #pragma unroll
            for (int j = 0; j < 2; ++j)
                b[j] = Bsv[h * 512 + (wn + j * 16 + arow16) * 4 + kgrp];
            #pragma unroll
            for (int i = 0; i < 4; ++i)
                #pragma unroll
                for (int j = 0; j < 2; ++j)
                    acc[i][j] = __builtin_amdgcn_mfma_f32_16x16x32_bf16(a[i], b[j], acc[i][j], 0, 0, 0);
        }
        __syncthreads();
    }

    const int drow = (lane >> 4) * 4;
    const int dcol = lane & 15;
    const bool isz = (n0 >= DI);
    __hip_bfloat16* dst = isz ? zh : xh;
    const int coloff = isz ? DI : 0;
    #pragma unroll
    for (int i = 0; i < 4; ++i)
        #pragma unroll
        for (int j = 0; j < 2; ++j) {
            int rowb = m0 + wm + i * 16 + drow;
            int col  = n0 + wn + j * 16 + dcol - coloff;
            #pragma unroll
            for (int r = 0; r < 4; ++r)
                dst[(size_t)(rowb + r) * DI + col] = __float2bfloat16(acc[i][j][r]);
        }
}

// ---------------- bf16 MFMA GEMM 64x64 tile, 512 thr, split-K, BK=64 (2 panels) ---------
template<bool RES>
__global__ __launch_bounds__(512) void gemm64_sk(const __hip_bfloat16* __restrict__ A,
                                                 const __hip_bfloat16* __restrict__ Bt,
                                                 const float* __restrict__ Res,
                                                 float* __restrict__ C,
                                                 int M, int N, int K) {
    __shared__ __hip_bfloat16 As[2][64 * 64];
    __shared__ __hip_bfloat16 Bs[2][64 * 64];
    __shared__ float red[256 * 17];
    const int tid  = threadIdx.x;
    const int wave = tid >> 6, lane = tid & 63;
    const int g = wave >> 2, w2 = wave & 3;
    const int m0 = blockIdx.y * 64, n0 = blockIdx.x * 64;
    const int wm = (w2 >> 1) * 32, wn = (w2 & 1) * 32;

    floatx4 acc[2][2] = {};

    const int arow16 = lane & 15;
    const int kgrp   = lane >> 4;
    const int kbeg   = g * (K / 2);

    for (int kk = 0; kk < K / 2; kk += 64) {
        int k0 = kbeg + kk;
        #pragma unroll
        for (int p = 0; p < 2; ++p) {
            int j = (w2 * 64 + lane) + p * 256;   // 0..511 chunk index within group
            int h = j >> 8, rs = j & 255;
            int row = rs >> 2, seg = rs & 3;
            int brow = n0 + row; if (brow >= N) brow = N - 1;
            const __hip_bfloat16* gA = A  + (size_t)(m0 + row) * K + k0 + h * 32 + seg * 8;
            const __hip_bfloat16* gB = Bt + (size_t)brow * K + k0 + h * 32 + seg * 8;
            __hip_bfloat16* lA = As[g] + (size_t)(w2 * 64 + p * 256) * 8;
            __hip_bfloat16* lB = Bs[g] + (size_t)(w2 * 64 + p * 256) * 8;
            __builtin_amdgcn_global_load_lds(
                (const __attribute__((address_space(1))) void*)gA,
                (__attribute__((address_space(3))) void*)lA, 16, 0, 0);
            __builtin_amdgcn_global_load_lds(
                (const __attribute__((address_space(1))) void*)gB,
                (__attribute__((address_space(3))) void*)lB, 16, 0, 0);
        }
        __syncthreads();

        const shortx8* Asv = (const shortx8*)As[g];
        const shortx8* Bsv = (const shortx8*)Bs[g];
        #pragma unroll
        for (int h = 0; h < 2; ++h) {
            shortx8 a[2], b[2];
            #pragma unroll
            for (int i = 0; i < 2; ++i)
                a[i] = Asv[h * 256 + (wm + i * 16 + arow16) * 4 + kgrp];
            #pragma unroll
            for (int j = 0; j < 2; ++j)
                b[j] = Bsv[h * 256 + (wn + j * 16 + arow16) * 4 + kgrp];
            #pragma unroll
            for (int i = 0; i < 2; ++i)
                #pragma unroll
                for (int j = 0; j < 2; ++j)
                    acc[i][j] = __builtin_amdgcn_mfma_f32_16x16x32_bf16(a[i], b[j], acc[i][j], 0, 0, 0);
        }
        __syncthreads();
    }

    int rbase = (w2 * 64 + lane) * 17;
    if (g == 1) {
        #pragma unroll
        for (int i = 0; i < 2; ++i)
            #pragma unroll
            for (int j = 0; j < 2; ++j)
                *(float4*)&red[rbase + (i * 2 + j) * 4] =
                    make_float4(acc[i][j][0], acc[i][j][1], acc[i][j][2], acc[i][j][3]);
    }
    __syncthreads();
    if (g == 0) {
        const int drow = (lane >> 4) * 4;
        const int dcol = lane & 15;
        #pragma unroll
        for (int i = 0; i < 2; ++i)
            #pragma unroll
            for (int j = 0; j < 2; ++j) {
                float4 part = *(const float4*)&red[rbase + (i * 2 + j) * 4];
                int rowb = m0 + wm + i * 16 + drow;
                int col  = n0 + wn + j * 16 + dcol;
                if (col < N) {
                    #pragma unroll
                    for (int r = 0; r < 4; ++r) {
                        size_t idx = (size_t)(rowb + r) * N + col;
                        float v = acc[i][j][r] + (&part.x)[r];
                        if (RES) v += Res[idx];
                        C[idx] = v;
                    }
                }
            }
    }
}

// ---------------- Tiled conv + silu + transposes ----------------
__global__ __launch_bounds__(256) void conv_tile(const __hip_bfloat16* __restrict__ xh,
                                                 const __hip_bfloat16* __restrict__ zh,
                                                 const float* __restrict__ cw,
                                                 const float* __restrict__ cb,
                                                 __hip_bfloat16* __restrict__ xcv_bf,
                                                 __hip_bfloat16* __restrict__ xcvT,
                                                 __hip_bfloat16* __restrict__ zgT) {
    __shared__ float xt[67][68];
    __shared__ float tb[64][65];    // conv+silu result [t][d]
    __shared__ float tb2[64][65];   // silu(z) [t][d]
    int t0 = blockIdx.x * 64, d0 = blockIdx.y * 64, b = blockIdx.z;
    int tid = threadIdx.x;
    size_t rowbase = (size_t)b * Lseq;

    for (int i = tid; i < 67 * 16; i += 256) {
        int r = i >> 4, j = i & 15;
        int t = t0 - 3 + r;
        float4 v4 = make_float4(0.f, 0.f, 0.f, 0.f);
        if (t >= 0) {
            ushort4 u = *(const ushort4*)&xh[(rowbase + t) * DI + d0 + j * 4];
            v4 = make_float4(bf2f(u.x), bf2f(u.y), bf2f(u.z), bf2f(u.w));
        }
        *(float4*)&xt[r][j * 4] = v4;
    }
    for (int i = tid; i < 64 * 16; i += 256) {
        int r = i >> 4, j = i & 15;
        ushort4 u = *(const ushort4*)&zh[(rowbase + t0 + r) * DI + d0 + j * 4];
        tb2[r][j * 4 + 0] = silu_f(bf2f(u.x));
        tb2[r][j * 4 + 1] = silu_f(bf2f(u.y));
        tb2[r][j * 4 + 2] = silu_f(bf2f(u.z));
        tb2[r][j * 4 + 3] = silu_f(bf2f(u.w));
    }
    __syncthreads();

    {
        int d = tid & 63, tg = tid >> 6;
        float4 cwv = *(const float4*)&cw[(d0 + d) * 4];
        float cbv = cb[d0 + d];
        #pragma unroll
        for (int i = 0; i < 16; ++i) {
            int t = tg * 16 + i;
            float acc = cbv;
            #pragma unroll
            for (int k = 0; k < 4; ++k) acc += xt[t + k][d] * (&cwv.x)[k];
            float v = silu_f(acc);
            tb[t][d] = v;
            xcv_bf[(rowbase + t0 + t) * DI + d0 + d] = __float2bfloat16(v);
        }
    }
    __syncthreads();

    {
        int t2 = tid & 63, dg2 = tid >> 6;
        #pragma unroll
        for (int i = 0; i < 16; ++i) {
            int d = dg2 * 16 + i;
            size_t orow = ((size_t)(b * DI + d0 + d)) * Lseq + t0 + t2;
            xcvT[orow] = __float2bfloat16(tb[t2][d]);
            zgT[orow]  = __float2bfloat16(tb2[t2][d]);
        }
    }
}

// ---------------- delta = softplus(dt @ W_dt + b_dt), 8 rows per block ----------------
__global__ __launch_bounds__(256) void delta_kernel(const float* __restrict__ xdb,
                                                    const float* __restrict__ Wdt,
                                                    const float* __restrict__ bdt,
                                                    float* __restrict__ delta) {
    int r0 = blockIdx.y * DROWS;
    int d = blockIdx.x * 256 + threadIdx.x;
    __shared__ float dtv[RNK][DROWS];   // [r][k] -> wave-uniform b128 reads
    if (threadIdx.x < DROWS * RNK) {
        int k = threadIdx.x >> 5, r = threadIdx.x & 31;
        dtv[r][k] = xdb[(size_t)(r0 + k) * XDBW + r];
    }
    __syncthreads();
    float bb = bdt[d];
    float acc[DROWS];
    #pragma unroll
    for (int k = 0; k < DROWS; ++k) acc[k] = bb;
    #pragma unroll
    for (int r = 0; r < RNK; ++r) {
        float wv = Wdt[(size_t)r * DI + d];
        float4 lo = *(const float4*)&dtv[r][0];
        float4 hi = *(const float4*)&dtv[r][4];
        acc[0] += lo.x * wv; acc[1] += lo.y * wv;
        acc[2] += lo.z * wv; acc[3] += lo.w * wv;
        acc[4] += hi.x * wv; acc[5] += hi.y * wv;
        acc[6] += hi.z * wv; acc[7] += hi.w * wv;
    }
    #pragma unroll
    for (int k = 0; k < DROWS; ++k) {
        float a = acc[k];
        float sp = (a > 20.f) ? a : log1pf(__expf(a));
        delta[(size_t)(r0 + k) * DI + d] = sp;
    }
}

// ============ Single-pass serial scan: DPP ring-sum reduce (no cross-lane shfl) ============
// v10 structure (global BC loads, proven conflict-clean, 78.2us) with the reduce
// restructured: v10's 3 serial __shfl_xor ds-ops (~300+ cyc chain tail per 8t, the
// measured latency bottleneck) are replaced by 16-lane DPP row_ror ring-sums
// (4x v_add_f32 DPP, pure VALU, ~4cyc each). Each 8-t group reduces in 2 passes of
// 4 t x 16 lanes; each lane reads 4 consecutive states (stride-65 scalar reads,
// 2-way bank-free). Lane l ends holding y for t = tmap(l) = 4*(l&15) + (l>>4);
// xv/zv/vd and the T-store use the same permutation (same cache lines, no cost).
__global__ __launch_bounds__(512) void scan_full(
        const float* __restrict__ delta, const __hip_bfloat16* __restrict__ xcvT,
        const float* __restrict__ xdb, const __hip_bfloat16* __restrict__ zgT,
        const float* __restrict__ A_log, const float* __restrict__ Dp,
        __hip_bfloat16* __restrict__ y_row) {
    __shared__ float dsh[2][64][9];    // [buf][t][ch] delta staging
    __shared__ float P[8][8 * 65];     // per-wave reduce scratch, odd stride 65
    __shared__ float T[64 * 9];        // y transpose staging [t][ch]

    int blk = blockIdx.x;              // Bn * DI/8 = 256
    int dg  = blk & 127;               // DI/8 = 128
    int b   = blk >> 7;
    int tid = threadIdx.x, w = tid >> 6, lane = tid & 63;
    int d = dg * 8 + w;

    float a2 = -__expf(A_log[d * DS + lane]) * LOG2E;  // exp(x) == exp2(x*log2e)
    float Dv = Dp[d];

    const int st_t = tid >> 3, st_d = tid & 7;
    const int tmap = 4 * (lane & 15) + (lane >> 4);    // this lane's output t in tile

    // stage tile-0 delta
    dsh[0][st_t][st_d] = delta[(size_t)(b * Lseq + st_t) * DI + dg * 8 + st_d];
    __syncthreads();

    const unsigned short* xT = (const unsigned short*)xcvT;
    const unsigned short* zT = (const unsigned short*)zgT;
    const size_t chbase = (size_t)(b * DI + d) * Lseq;

    float xv = bf2f(xT[chbase + tmap]);   // tile 0 x/z at this lane's output t
    float zv = bf2f(zT[chbase + tmap]);

    float h = 0.f;
    float* Pw = P[w];
    const int rr = lane >> 4;          // reduce row-group (t row within pass)
    const int j4 = (lane & 15) * 4;    // state quad base
    const int selt8 = (lane & 15) >> 1;
    const int selp  = lane & 1;

    // per-lane B/C column pointers: B_t[lane] = Bcol[t*XDBW] (coalesced across lanes)
    const float* Bcol = xdb + RNK + lane;
    const float* Ccol = xdb + RNK + DS + lane;

    // preload group 0 of tile 0 into set A (groups of 16 t; 4 groups/tile)
    float bA[16], cA[16], bB[16], cB[16];
    #pragma unroll
    for (int k = 0; k < 16; ++k) {
        bA[k] = Bcol[(size_t)(b * Lseq + k) * XDBW];
        cA[k] = Ccol[(size_t)(b * Lseq + k) * XDBW];
    }

    for (int c = 0; c < NC; ++c) {
        int cur = c & 1;

        // tile-level prefetch (x, z, delta for tile c+1)
        float pd = 0.f, nxv = 0.f, nzv = 0.f;
        if (c + 1 < NC) {
            int r1 = b * Lseq + (c + 1) * CH;
            pd  = delta[(size_t)(r1 + st_t) * DI + dg * 8 + st_d];
            nxv = bf2f(xT[chbase + (c + 1) * CH + tmap]);
            nzv = bf2f(zT[chbase + (c + 1) * CH + tmap]);
        }

        int r0 = b * Lseq + c * CH;
        int rnext = (c + 1 < NC) ? (r0 + CH) : r0;   // clamped: last tile reloads valid addrs

        float vd  = dsh[cur][tmap][w];   // delta at this lane's output t
        float vpx = vd * xv;             // delta_t * x_t
        float y = 0.f;

        #pragma unroll
        for (int g4 = 0; g4 < 4; ++g4) {
            // issue next-group loads into the other register set (hoisted above chain)
            int rg = (g4 < 3) ? (r0 + (g4 + 1) * 16) : rnext;
            if ((g4 & 1) == 0) {
                #pragma unroll
                for (int k = 0; k < 16; ++k) {
                    bB[k] = Bcol[(size_t)(rg + k) * XDBW];
                    cB[k] = Ccol[(size_t)(rg + k) * XDBW];
                }
            } else {
                #pragma unroll
                for (int k = 0; k < 16; ++k) {
                    bA[k] = Bcol[(size_t)(rg + k) * XDBW];
                    cA[k] = Ccol[(size_t)(rg + k) * XDBW];
                }
            }
            // compute this group's 16 t (two 8-t recurrence+reduce sub-chunks)
            #pragma unroll
            for (int half = 0; half < 2; ++half) {
                int t8g = g4 * 2 + half;
                #pragma unroll
                for (int kk = 0; kk < 8; ++kk) {
                    int k = half * 8 + kk;
                    int t = g4 * 16 + k;
                    float Bv = ((g4 & 1) == 0) ? bA[k] : bB[k];
                    float Cv = ((g4 & 1) == 0) ? cA[k] : cB[k];
                    h = h * exp2_fast(rdl(vd, invl(t)) * a2) + rdl(vpx, invl(t)) * Bv;
                    Pw[kk * 65 + lane] = h * Cv;
                }
                // reduce 8 t's: 2 passes of {4 t rows x 16 lanes, 4 states/lane}
                #pragma unroll
                for (int p = 0; p < 2; ++p) {
                    int prow = p * 4 + rr;
                    float s0 = Pw[prow * 65 + j4];
                    float s1 = Pw[prow * 65 + j4 + 1];
                    float s2 = Pw[prow * 65 + j4 + 2];
                    float s3 = Pw[prow * 65 + j4 + 3];
                    float part = ((s0 + s1) + s2) + s3;
                    part = ror_add16<1>(part);
                    part = ror_add16<2>(part);
                    part = ror_add16<4>(part);
                    part = ror_add16<8>(part);
                    if (t8g == selt8 && p == selp) y = part;  // lane l keeps y[tmap(l)]
                }
            }
        }

        float yv = (y + xv * Dv) * zv;

        __syncthreads();   // all waves done with prior tile's T reads
        T[tmap * 9 + w] = yv;
        if (c + 1 < NC) dsh[cur ^ 1][st_t][st_d] = pd;
        __syncthreads();   // T + next dsh visible to all

        // coalesced y_row write from T (natural order)
        {
            float v = T[st_t * 9 + st_d];
            y_row[(size_t)(r0 + st_t) * DI + dg * 8 + st_d] = __float2bfloat16(v);
        }

        xv = nxv; zv = nzv;
    }
}

extern "C" void kernel_launch(void* const* d_in, const int* in_sizes, int n_in,
                              void* d_out, int out_size, void* d_ws, size_t ws_size,
                              hipStream_t stream) {
    const float* frames = (const float*)d_in[0];
    const float* gamma  = (const float*)d_in[1];
    const float* beta   = (const float*)d_in[2];
    const float* W_in   = (const float*)d_in[3];
    const float* conv_w = (const float*)d_in[4];
    const float* conv_b = (const float*)d_in[5];
    const float* W_x    = (const float*)d_in[6];
    const float* W_dt   = (const float*)d_in[7];
    const float* b_dt   = (const float*)d_in[8];
    const float* A_log  = (const float*)d_in[9];
    const float* Dp     = (const float*)d_in[10];
    const float* W_out  = (const float*)d_in[11];
    float* out = (float*)d_out;

    // workspace carve-up (bytes)
    char* ws = (char*)d_ws;
    __hip_bfloat16* xn_bf  = (__hip_bfloat16*)ws; ws += (size_t)NROWS * DM * 2;
    __hip_bfloat16* Wt_in  = (__hip_bfloat16*)ws; ws += (size_t)(2 * DI) * DM * 2;
    __hip_bfloat16* Wt_out = (__hip_bfloat16*)ws; ws += (size_t)DM * DI * 2;
    __hip_bfloat16* Wt_x   = (__hip_bfloat16*)ws; ws += (size_t)XDBW * DI * 2;
    __hip_bfloat16* y_row  = (__hip_bfloat16*)ws; ws += (size_t)NROWS * DI * 2;
    __hip_bfloat16* xcv_bf = (__hip_bfloat16*)ws; ws += (size_t)NROWS * DI * 2;
    __hip_bfloat16* xh     = (__hip_bfloat16*)ws; ws += (size_t)NROWS * DI * 2;
    __hip_bfloat16* zh     = (__hip_bfloat16*)ws; ws += (size_t)NROWS * DI * 2;
    __hip_bfloat16* xcvT   = (__hip_bfloat16*)ws; ws += (size_t)NROWS * DI * 2;
    __hip_bfloat16* zgT    = (__hip_bfloat16*)ws; ws += (size_t)NROWS * DI * 2;
    float* xdb    = (float*)ws;  ws += (size_t)NROWS * XDBW * 4;
    float* delta  = (float*)ws;  ws += (size_t)NROWS * DI * 4;

    // fused LN + weight transposes
    prep_kernel<<<NROWS + 432, 256, 0, stream>>>(frames, gamma, beta, W_in, W_out, W_x,
                                                 xn_bf, Wt_in, Wt_out, Wt_x);

    // in_proj -> bf16 x-half / z-half (BK=64)
    gemm_inproj<<<dim3(2 * DI / 128, NROWS / 128), 512, 0, stream>>>(
        xn_bf, Wt_in, xh, zh, NROWS, 2 * DI, DM);

    // conv + silu + transposes
    conv_tile<<<dim3(Lseq / 64, DI / 64, Bn), 256, 0, stream>>>(
        xh, zh, conv_w, conv_b, xcv_bf, xcvT, zgT);

    // xdb = xcv @ W_x  (M=2048, N=160, K=1024, BK=64 split-K)
    gemm64_sk<false><<<dim3((XDBW + 63) / 64, NROWS / 64), 512, 0, stream>>>(
        xcv_bf, Wt_x, nullptr, xdb, NROWS, XDBW, DI);

    delta_kernel<<<dim3(DI / 256, NROWS / DROWS), 256, 0, stream>>>(xdb, W_dt, b_dt, delta);

    // single-pass serial selective scan
    scan_full<<<Bn * (DI / 8), 512, 0, stream>>>(delta, xcvT, xdb, zgT, A_log, Dp, y_row);

    // out_proj: out = y_row @ W_out + frames (BK=64 split-K)
    gemm64_sk<true><<<dim3(DM / 64, NROWS / 64), 512, 0, stream>>>(
        y_row, Wt_out, frames, out, NROWS, DM, DI);
}